// Round 14
// baseline (506.057 us; speedup 1.0000x reference)
//
#include <hip/hip_runtime.h>

#define E_EDGES 250000
#define NHRU 100000
#define NCH  40000
#define NGW  60000
#define NCNT 280000
#define NBLK_SCAN 1094

// fused_pre block layout: cvt grid-stride (1024) | count (5*977) | prep (3076)
#define NB_E      977
#define NB_CNT    (5 * NB_E)
#define NB_CVTGS  1024
#define NB_PREP   3076

typedef __attribute__((ext_vector_type(4))) float f32x4;
typedef __attribute__((ext_vector_type(2))) float f32x2;
typedef __attribute__((ext_vector_type(8))) __bf16 bf16x8;
typedef __attribute__((ext_vector_type(8))) short short8;

__device__ __forceinline__ float bf2f(short h) {
  unsigned u = ((unsigned)(unsigned short)h) << 16;
  return __builtin_bit_cast(float, u);
}
__device__ __forceinline__ short f2bf(float f) {
  unsigned u = __builtin_bit_cast(unsigned, f);
  u = u + 0x7fffu + ((u >> 16) & 1u);
  return (short)(u >> 16);
}

__device__ __forceinline__ void load_lds16(const void* g, void* lds) {
  __builtin_amdgcn_global_load_lds(
      (const __attribute__((address_space(1))) unsigned*)g,
      (__attribute__((address_space(3))) unsigned*)lds, 16, 0, 0);
}

struct P5 { const int* p[5]; };

// ---------------- fused front-end: cvt(grid-stride) | count_rank | prep_w ----------------
// cvt uses 1024 persistent blocks (4/CU, half occupancy) so count+prep blocks
// co-schedule on the same CUs -> latency-bound atomics hide under the BW stream.
__global__ void fused_pre(const float* __restrict__ xh, const float* __restrict__ xc,
                          const float* __restrict__ xg, short* __restrict__ oh,
                          short* __restrict__ oc, short* __restrict__ og,
                          const float* __restrict__ Wl, const float* __restrict__ Wr,
                          const float* __restrict__ bs, short* __restrict__ Bt,
                          float* __restrict__ bias,
                          P5 dst, int* __restrict__ cnt, int* __restrict__ rank) {
  int b = blockIdx.x;
  if (b < NB_CVTGS) {
    // ---- fp32 -> bf16 convert: grid-stride, 64B units ----
    const int m1 = NHRU * 16, m2 = m1 + NCH * 16, m3 = m2 + NGW * 16;
    for (int u = b * 256 + threadIdx.x; u < m3; u += NB_CVTGS * 256) {
      const float* in; short* out; int j;
      if (u < m1) { in = xh; out = oh; j = u; }
      else if (u < m2) { in = xc; out = oc; j = u - m1; }
      else { in = xg; out = og; j = u - m2; }
      const f32x4* p = reinterpret_cast<const f32x4*>(in) + (size_t)j * 4;
      f32x4 v0 = __builtin_nontemporal_load(p);
      f32x4 v1 = __builtin_nontemporal_load(p + 1);
      f32x4 v2 = __builtin_nontemporal_load(p + 2);
      f32x4 v3 = __builtin_nontemporal_load(p + 3);
      short8 o0, o1;
#pragma unroll
      for (int k = 0; k < 4; ++k) {
        o0[k] = f2bf(v0[k]); o0[4 + k] = f2bf(v1[k]);
        o1[k] = f2bf(v2[k]); o1[4 + k] = f2bf(v3[k]);
      }
      reinterpret_cast<short8*>(out)[2 * j] = o0;
      reinterpret_cast<short8*>(out)[2 * j + 1] = o1;
    }
  } else if (b < NB_CVTGS + NB_CNT) {
    // ---- count + rank (latency-bound; co-resident with cvt blocks) ----
    const int COFF[5] = {0, 60000, 100000, 140000, 180000};
    int bb = b - NB_CVTGS;
    int r = bb / NB_E;
    int e = (bb - r * NB_E) * 256 + threadIdx.x;
    if (e < E_EDGES) {
      int d = dst.p[r][e];
      int rk = atomicAdd(&cnt[COFF[r] + d], 1);
      rank[r * E_EDGES + e] = rk;
    }
  } else {
    // ---- weight prep: transpose + bf16 + fold /3 ----
    int i = (b - NB_CVTGS - NB_CNT) * 256 + threadIdx.x;
    const float inv3 = 1.0f / 3.0f;
    if (i < 131072) {                       // gw: l=0,r=0
      int n = i >> 9, k = i & 511;
      float v = (k < 256) ? Wl[(0 * 256 + k) * 256 + n]
                          : Wr[(0 * 256 + (k - 256)) * 256 + n];
      Bt[i] = f2bf(v);
    } else if (i < 393216) {                // ch l=0
      int j = i - 131072;
      int n = j >> 10, k = j & 1023;
      float v;
      if (k < 768) {
        int r = 1 + (k >> 8), kk = k & 255;
        v = Wl[((0 * 5 + r) * 256 + kk) * 256 + n] * inv3;
      } else {
        int kk = k - 768;
        v = (Wr[((0 * 5 + 1) * 256 + kk) * 256 + n] +
             Wr[((0 * 5 + 2) * 256 + kk) * 256 + n] +
             Wr[((0 * 5 + 3) * 256 + kk) * 256 + n]) * inv3;
      }
      Bt[i] = f2bf(v);
    } else if (i < 524288) {                // hru: l=0,r=4
      int j = i - 393216;
      int n = j >> 9, k = j & 511;
      float v = (k < 256) ? Wl[((0 * 5 + 4) * 256 + k) * 256 + n]
                          : Wr[((0 * 5 + 4) * 256 + (k - 256)) * 256 + n];
      Bt[i] = f2bf(v);
    } else if (i < 786432) {                // ch l=1
      int j = i - 524288;
      int n = j >> 10, k = j & 1023;
      float v;
      if (k < 768) {
        int r = 1 + (k >> 8), kk = k & 255;
        v = Wl[((5 + r) * 256 + kk) * 256 + n] * inv3;
      } else {
        int kk = k - 768;
        v = (Wr[((5 + 1) * 256 + kk) * 256 + n] +
             Wr[((5 + 2) * 256 + kk) * 256 + n] +
             Wr[((5 + 3) * 256 + kk) * 256 + n]) * inv3;
      }
      Bt[i] = f2bf(v);
    } else if (i < 787456) {                // biases
      int j = i - 786432;
      int g = j >> 8, n = j & 255;
      float v;
      if (g == 0)      v = bs[n];
      else if (g == 1) v = (bs[256 + n] + bs[512 + n] + bs[768 + n]) * inv3;
      else if (g == 2) v = bs[1024 + n];
      else             v = (bs[1280 + 256 + n] + bs[1280 + 512 + n] + bs[1280 + 768 + n]) * inv3;
      bias[j] = v;
    }
  }
}

// ---------------- global scan (3 kernels) ----------------
__global__ void scan_a(const int* __restrict__ cnt, int* __restrict__ bsum) {
  int i = blockIdx.x * 256 + threadIdx.x;
  int v = (i < NCNT) ? cnt[i] : 0;
  int lane = threadIdx.x & 63, wv = threadIdx.x >> 6;
  for (int d = 1; d < 64; d <<= 1) v += __shfl_down(v, d);
  __shared__ int ws[4];
  if (lane == 0) ws[wv] = v;
  __syncthreads();
  if (threadIdx.x == 0) bsum[blockIdx.x] = ws[0] + ws[1] + ws[2] + ws[3];
}

__global__ void scan_b(const int* __restrict__ bsum, int* __restrict__ boff) {
  int t = threadIdx.x;
  int e0 = 2 * t, e1 = 2 * t + 1;
  int v0 = (e0 < NBLK_SCAN) ? bsum[e0] : 0;
  int v1 = (e1 < NBLK_SCAN) ? bsum[e1] : 0;
  __shared__ int lds[1024];
  lds[t] = v0 + v1;
  __syncthreads();
  for (int o = 1; o < 1024; o <<= 1) {
    int add = (t >= o) ? lds[t - o] : 0;
    __syncthreads();
    lds[t] += add;
    __syncthreads();
  }
  int ex = (t == 0) ? 0 : lds[t - 1];
  if (e0 < NBLK_SCAN) boff[e0] = ex;
  if (e1 < NBLK_SCAN) boff[e1] = ex + v0;
}

__global__ void scan_c(const int* __restrict__ cnt, const int* __restrict__ boff,
                       int* __restrict__ S) {
  int i = blockIdx.x * 256 + threadIdx.x;
  int v = (i < NCNT) ? cnt[i] : 0;
  int lane = threadIdx.x & 63, wv = threadIdx.x >> 6;
  int inc = v;
  for (int d = 1; d < 64; d <<= 1) {
    int y = __shfl_up(inc, d);
    if (lane >= d) inc += y;
  }
  __shared__ int ws[4];
  if (lane == 63) ws[wv] = inc;
  __syncthreads();
  int wex = 0;
  for (int k = 0; k < 4; ++k) wex += (k < wv) ? ws[k] : 0;
  int ex = boff[blockIdx.x] + wex + inc - v;
  if (i < NCNT) S[i] = ex;
  if (blockIdx.x == 0 && threadIdx.x == 0) S[NCNT] = 5 * E_EDGES;
}

// pass 2: scatter without atomics
__global__ void scatter_kernel(P5 src, P5 dst, const int* __restrict__ rp,
                               const int* __restrict__ rank, int* __restrict__ ssrc) {
  const int COFF[5] = {0, 60000, 100000, 140000, 180000};
  int r = blockIdx.y;
  int e = blockIdx.x * blockDim.x + threadIdx.x;
  if (e < E_EDGES) {
    int d = dst.p[r][e];
    int idx = rp[COFF[r] + d] + rank[r * E_EDGES + e];
    ssrc[idx] = src.p[r][e];
  }
}

// ---------------- paired mean aggregation: 2 items/wave, 2 gather chains per half ----------------
// 5-range relation decode; single dispatch per layer (R11 structure).
struct AggTab { const short* src[5]; short* out[5]; };

__global__ void agg_pair(const int* __restrict__ rp, const int* __restrict__ ssrc,
                         AggTab tab, int be0, int be1, int be2, int be3,
                         int r0, int r1, int r2, int r3, int r4) {
  int b = blockIdx.x;
  int r, b0;
  if (b < be0)      { r = r0; b0 = 0; }
  else if (b < be1) { r = r1; b0 = be0; }
  else if (b < be2) { r = r2; b0 = be1; }
  else if (b < be3) { r = r3; b0 = be2; }
  else              { r = r4; b0 = be3; }
  int coff = r == 0 ? 0 : r == 1 ? 60000 : r == 2 ? 100000 : r == 3 ? 140000 : 180000;
  int nrel = r == 0 ? 60000 : r == 4 ? 100000 : 40000;
  const short* xs = r == 0 ? tab.src[0] : r == 1 ? tab.src[1] : r == 2 ? tab.src[2]
                   : r == 3 ? tab.src[3] : tab.src[4];
  short* ob = r == 0 ? tab.out[0] : r == 1 ? tab.out[1] : r == 2 ? tab.out[2]
             : r == 3 ? tab.out[3] : tab.out[4];

  int wid = threadIdx.x >> 6;
  int lane = threadIdx.x & 63;
  int half = lane >> 5, l32 = lane & 31;
  int row = (b - b0) * 8 + wid * 2 + half;          // per-half item
  bool active = row < nrel;
  int item = coff + row;
  int lo = 0, hi = 0;
  if (active) { lo = rp[item]; hi = rp[item + 1]; }

  f32x2 a0[4], a1[4];
#pragma unroll
  for (int k = 0; k < 4; ++k) { a0[k] = (f32x2){0.f, 0.f}; a1[k] = (f32x2){0.f, 0.f}; }
  int e = lo;
  for (; e + 1 < hi; e += 2) {                      // 2 independent chains per half
    int s0 = ssrc[e];
    int s1 = ssrc[e + 1];
    uint4 u0 = *reinterpret_cast<const uint4*>(xs + (size_t)s0 * 256 + l32 * 8);
    uint4 u1 = *reinterpret_cast<const uint4*>(xs + (size_t)s1 * 256 + l32 * 8);
    unsigned d0[4] = {u0.x, u0.y, u0.z, u0.w};
    unsigned d1[4] = {u1.x, u1.y, u1.z, u1.w};
#pragma unroll
    for (int k = 0; k < 4; ++k) {
      a0[k] += (f32x2){__builtin_bit_cast(float, d0[k] << 16),
                       __builtin_bit_cast(float, d0[k] & 0xffff0000u)};
      a1[k] += (f32x2){__builtin_bit_cast(float, d1[k] << 16),
                       __builtin_bit_cast(float, d1[k] & 0xffff0000u)};
    }
  }
  if (e < hi) {
    int s = ssrc[e];
    uint4 u = *reinterpret_cast<const uint4*>(xs + (size_t)s * 256 + l32 * 8);
    unsigned d[4] = {u.x, u.y, u.z, u.w};
#pragma unroll
    for (int k = 0; k < 4; ++k) {
      a0[k] += (f32x2){__builtin_bit_cast(float, d[k] << 16),
                       __builtin_bit_cast(float, d[k] & 0xffff0000u)};
    }
  }
#pragma unroll
  for (int k = 0; k < 4; ++k) a0[k] += a1[k];
  if (active) {
    int c = hi - lo; if (c < 1) c = 1;
    float inv = 1.0f / (float)c;
    short8 o;
#pragma unroll
    for (int k = 0; k < 4; ++k) {
      o[2 * k] = f2bf(a0[k].x * inv);
      o[2 * k + 1] = f2bf(a0[k].y * inv);
    }
    *reinterpret_cast<short8*>(ob + (size_t)row * 256 + l32 * 8) = o;
  }
}

// ---------------- bf16 MFMA GEMM: BM=128, BN=256, BK=64, 8 waves ----------------
struct Srcs4 { const short* s[4]; };
struct GArgs {
  Srcs4 srcs; const short* Bt; const float* bias;
  int M; int K; short* outb; float* outf;
};

__device__ __forceinline__ void gemm_body(const GArgs& a, int bx) {
  __shared__ short sm[24576];          // A @0 (128*64), B @8192 (256*64); reused by epilogue
  short* Asm = sm;
  short* Bsm = sm + 8192;
  const int tid = threadIdx.x;
  const int lane = tid & 63;
  const int w = tid >> 6;             // 0..7
  const int wr = w >> 2, wc = w & 3;  // 2 x 4 wave grid
  const int m0 = bx * 128;
  const int M = a.M, K = a.K;

  f32x4 acc[4][4];
#pragma unroll
  for (int i = 0; i < 4; ++i)
#pragma unroll
    for (int j = 0; j < 4; ++j) acc[i][j] = (f32x4){0.f, 0.f, 0.f, 0.f};

  for (int k0 = 0; k0 < K; k0 += 64) {
    const short* Aq = a.srcs.s[k0 >> 8];
    const int kc = k0 & 255;
#pragma unroll
    for (int rr = 0; rr < 2; ++rr) {
      const int rbase = w * 16 + rr * 8;
      const int row = rbase + (lane >> 3);
      const int cs = ((lane & 7) ^ (row & 7)) << 3;
      int gr = m0 + row; gr = gr < M ? gr : M - 1;
      load_lds16(Aq + (size_t)gr * 256 + kc + cs, &Asm[rbase * 64]);
    }
#pragma unroll
    for (int rr = 0; rr < 4; ++rr) {
      const int rbase = w * 32 + rr * 8;
      const int row = rbase + (lane >> 3);
      const int cs = ((lane & 7) ^ (row & 7)) << 3;
      load_lds16(a.Bt + (size_t)row * K + k0 + cs, &Bsm[rbase * 64]);
    }
    __syncthreads();
#pragma unroll
    for (int h = 0; h < 2; ++h) {
      const int cg = (h << 2) + (lane >> 4);
      bf16x8 af[4], bfr[4];
#pragma unroll
      for (int mi = 0; mi < 4; ++mi) {
        const int r = wr * 64 + mi * 16 + (lane & 15);
        af[mi] = *reinterpret_cast<const bf16x8*>(&Asm[r * 64 + ((cg ^ (r & 7)) << 3)]);
      }
#pragma unroll
      for (int nj = 0; nj < 4; ++nj) {
        const int r = wc * 64 + nj * 16 + (lane & 15);
        bfr[nj] = *reinterpret_cast<const bf16x8*>(&Bsm[r * 64 + ((cg ^ (r & 7)) << 3)]);
      }
#pragma unroll
      for (int mi = 0; mi < 4; ++mi)
#pragma unroll
        for (int nj = 0; nj < 4; ++nj)
          acc[mi][nj] = __builtin_amdgcn_mfma_f32_16x16x32_bf16(af[mi], bfr[nj], acc[mi][nj], 0, 0, 0);
    }
    __syncthreads();
  }

  const int rb = (lane >> 4) << 2;
  const int cl = lane & 15;

  if (a.outb) {
#pragma unroll
    for (int halfp = 0; halfp < 2; ++halfp) {
      __syncthreads();
      if (wr == halfp) {
#pragma unroll
        for (int mi = 0; mi < 4; ++mi)
#pragma unroll
          for (int nj = 0; nj < 4; ++nj) {
            const int col = wc * 64 + nj * 16 + cl;
            const float bv = a.bias[col];
#pragma unroll
            for (int j = 0; j < 4; ++j) {
              const int rloc = mi * 16 + rb + j;
              float v = fmaxf(acc[mi][nj][j] + bv, 0.0f);
              sm[rloc * 264 + col] = f2bf(v);
            }
          }
      }
      __syncthreads();
#pragma unroll
      for (int q = 0; q < 4; ++q) {
        int c = q * 512 + tid;
        int rloc = c >> 5;
        int coff = (c & 31) * 8;
        int grow = m0 + halfp * 64 + rloc;
        if (grow < M) {
          short8 vv = *reinterpret_cast<const short8*>(&sm[rloc * 264 + coff]);
          *reinterpret_cast<short8*>(a.outb + (size_t)grow * 256 + coff) = vv;
        }
      }
    }
  }
  if (a.outf) {
    float* fsm = reinterpret_cast<float*>(sm);
#pragma unroll
    for (int p = 0; p < 4; ++p) {
      __syncthreads();
      if (wr == (p >> 1)) {
#pragma unroll
        for (int mm = 0; mm < 2; ++mm) {
          const int mi = (p & 1) * 2 + mm;
#pragma unroll
          for (int nj = 0; nj < 4; ++nj) {
            const int col = wc * 64 + nj * 16 + cl;
            const float bv = a.bias[col];
#pragma unroll
            for (int j = 0; j < 4; ++j) {
              const int rloc = mi * 16 + rb + j - (p & 1) * 32;
              float v = fmaxf(acc[mi][nj][j] + bv, 0.0f);
              fsm[rloc * 260 + col] = v;
            }
          }
        }
      }
      __syncthreads();
#pragma unroll
      for (int q = 0; q < 4; ++q) {
        int c = q * 512 + tid;
        int rloc = c >> 6;
        int coff = (c & 63) * 4;
        int grow = m0 + p * 32 + rloc;
        if (grow < M) {
          float4 vv = *reinterpret_cast<const float4*>(&fsm[rloc * 260 + coff]);
          *reinterpret_cast<float4*>(a.outf + (size_t)grow * 256 + coff) = vv;
        }
      }
    }
  }
}

__global__ __launch_bounds__(512) void gemm_bt(GArgs a) {
  gemm_body(a, blockIdx.x);
}

__global__ __launch_bounds__(512) void gemm_multi3(GArgs a0, GArgs a1, GArgs a2,
                                                   int nb0, int nb01) {
  int bx = blockIdx.x;
  if (bx < nb0) gemm_body(a0, bx);
  else if (bx < nb01) gemm_body(a1, bx - nb0);
  else gemm_body(a2, bx - nb01);
}

// ---------------- pooling (two-stage) + MLP ----------------
__device__ __forceinline__ int lower_bound(const int* a, int n, int v) {
  int lo = 0, hi = n;
  while (lo < hi) { int mid = (lo + hi) >> 1; if (a[mid] < v) lo = mid + 1; else hi = mid; }
  return lo;
}

__global__ void pool_partial(const float* __restrict__ c2, const int* __restrict__ batch,
                             float* __restrict__ pooled_sum) {
  int r0 = blockIdx.x * 64;
  int t = threadIdx.x;
  float acc = 0.f;
  int prevb = batch[r0];
  for (int i = 0; i < 64; ++i) {
    int r = r0 + i;
    int b = batch[r];
    if (b != prevb) {
      atomicAdd(&pooled_sum[prevb * 256 + t], acc);
      acc = 0.f; prevb = b;
    }
    acc += c2[(size_t)r * 256 + t];
  }
  atomicAdd(&pooled_sum[prevb * 256 + t], acc);
}

__global__ void mlp_kernel(const float* __restrict__ pooled_sum, const int* __restrict__ batch,
                           const float* __restrict__ train,
                           const float* __restrict__ fc1w, const float* __restrict__ fc1b,
                           const float* __restrict__ fc2w, const float* __restrict__ fc2b,
                           float* __restrict__ out) {
  int b = blockIdx.x, t = threadIdx.x;
  __shared__ float x[288];
  __shared__ float hsm[128];
  __shared__ float sinv;
  if (t == 0) {
    int lo = lower_bound(batch, NCH, b);
    int hi = lower_bound(batch, NCH, b + 1);
    int c = hi - lo; if (c < 1) c = 1;
    sinv = 1.0f / (float)c;
  }
  __syncthreads();
  float inv = sinv;
  x[t] = pooled_sum[b * 256 + t] * inv;
  x[128 + t] = pooled_sum[b * 256 + 128 + t] * inv;
  if (t < 32) x[256 + t] = train[b * 32 + t];
  __syncthreads();
  float s = fc1b[t];
  for (int i = 0; i < 288; ++i) s += x[i] * fc1w[i * 128 + t];
  hsm[t] = fmaxf(s, 0.f);
  __syncthreads();
  if (t < 16) {
    float o = fc2b[t];
    for (int i = 0; i < 128; ++i) o += hsm[i] * fc2w[i * 16 + t];
    out[b * 16 + t] = o;
  }
}

// ---------------- launch ----------------
extern "C" void kernel_launch(void* const* d_in, const int* in_sizes, int n_in,
                              void* d_out, int out_size, void* d_ws, size_t ws_size,
                              hipStream_t stream) {
  const float* x_hru = (const float*)d_in[0];
  const float* x_ch  = (const float*)d_in[1];
  const float* x_gw  = (const float*)d_in[2];
  const int* src_swgw = (const int*)d_in[3];
  const int* dst_swgw = (const int*)d_in[4];
  const int* src_hyd  = (const int*)d_in[5];
  const int* dst_hyd  = (const int*)d_in[6];
  const int* src_sw   = (const int*)d_in[7];
  const int* dst_sw   = (const int*)d_in[8];
  const int* src_gwsw = (const int*)d_in[9];
  const int* dst_gwsw = (const int*)d_in[10];
  const int* src_slf  = (const int*)d_in[11];
  const int* dst_slf  = (const int*)d_in[12];
  const int* batch    = (const int*)d_in[13];
  const float* train  = (const float*)d_in[14];
  const float* Wl     = (const float*)d_in[15];
  const float* Wr     = (const float*)d_in[16];
  const float* bs     = (const float*)d_in[17];
  const float* fc1w   = (const float*)d_in[18];
  const float* fc1b   = (const float*)d_in[19];
  const float* fc2w   = (const float*)d_in[20];
  const float* fc2b   = (const float*)d_in[21];
  float* out = (float*)d_out;

  char* ws = (char*)d_ws;
  size_t off = 0;
  auto alloc = [&](size_t bytes) -> void* {
    off = (off + 255) & ~(size_t)255;
    void* p = ws + off;
    off += bytes;
    return p;
  };

  short* xb0h = (short*)alloc((size_t)NHRU * 256 * 2);
  short* xb0c = (short*)alloc((size_t)NCH * 256 * 2);
  short* xb0g = (short*)alloc((size_t)NGW * 256 * 2);
  short* xb1h = (short*)alloc((size_t)NHRU * 256 * 2);
  short* xb1c = (short*)alloc((size_t)NCH * 256 * 2);
  short* xb1g = (short*)alloc((size_t)NGW * 256 * 2);
  short* agg_gw  = (short*)alloc((size_t)NGW * 256 * 2);
  short* agg_c0  = (short*)alloc((size_t)NCH * 256 * 2);
  short* agg_c1  = (short*)alloc((size_t)NCH * 256 * 2);
  short* agg_c2  = (short*)alloc((size_t)NCH * 256 * 2);
  short* agg_hru = (short*)alloc((size_t)NHRU * 256 * 2);
  float* c2f = (float*)alloc((size_t)NCH * 256 * 4);
  int* cnt  = (int*)alloc(NCNT * 4);
  int* rp   = (int*)alloc((NCNT + 1) * 4);
  int* rank = (int*)alloc((size_t)5 * E_EDGES * 4);
  int* bsum = (int*)alloc(NBLK_SCAN * 4);
  int* boff = (int*)alloc(NBLK_SCAN * 4);
  int* ssrc = (int*)alloc((size_t)5 * E_EDGES * 4);
  short* BtBuf = (short*)alloc(786432 * 2);
  float* biasBuf = (float*)alloc(1024 * 4);
  float* pooled_sum = (float*)alloc(64 * 256 * 4);

  hipMemsetAsync(cnt, 0, NCNT * 4, stream);
  hipMemsetAsync(pooled_sum, 0, 64 * 256 * 4, stream);

  P5 dsts; dsts.p[0] = dst_swgw; dsts.p[1] = dst_hyd; dsts.p[2] = dst_sw;
  dsts.p[3] = dst_gwsw; dsts.p[4] = dst_slf;
  P5 srcs; srcs.p[0] = src_swgw; srcs.p[1] = src_hyd; srcs.p[2] = src_sw;
  srcs.p[3] = src_gwsw; srcs.p[4] = src_slf;

  // fused front-end: cvt grid-stride (half occupancy) | count_rank | prep_w
  fused_pre<<<NB_CVTGS + NB_CNT + NB_PREP, 256, 0, stream>>>(
      x_hru, x_ch, x_gw, xb0h, xb0c, xb0g,
      Wl, Wr, bs, BtBuf, biasBuf, dsts, cnt, rank);

  scan_a<<<NBLK_SCAN, 256, 0, stream>>>(cnt, bsum);
  scan_b<<<1, 1024, 0, stream>>>(bsum, boff);
  scan_c<<<NBLK_SCAN, 256, 0, stream>>>(cnt, boff, rp);
  dim3 eg(NB_E, 5);
  scatter_kernel<<<eg, 256, 0, stream>>>(srcs, dsts, rp, rank, ssrc);

  // layer 1: all 5 relations, single dispatch (R11 structure)
  {
    AggTab t0{};
    t0.src[0] = xb0h; t0.out[0] = agg_gw;
    t0.src[1] = xb0c; t0.out[1] = agg_c0;
    t0.src[2] = xb0h; t0.out[2] = agg_c1;
    t0.src[3] = xb0g; t0.out[3] = agg_c2;
    t0.src[4] = xb0h; t0.out[4] = agg_hru;
    // blocks: gw 7500 | hyd 5000 | sw 5000 | gwsw 5000 | slf 12500
    agg_pair<<<35000, 256, 0, stream>>>(rp, ssrc, t0, 7500, 12500, 17500, 22500, 0, 1, 2, 3, 4);
  }

  // layer 1 GEMMs (merged, ch-first for tail balance: ch | gw | hru)
  {
    GArgs g0{}, g1{}, g2{};
    g0.srcs.s[0] = agg_c0; g0.srcs.s[1] = agg_c1; g0.srcs.s[2] = agg_c2; g0.srcs.s[3] = xb0c;
    g0.Bt = BtBuf + 131072; g0.bias = biasBuf + 256; g0.M = NCH; g0.K = 1024;
    g0.outb = xb1c; g0.outf = nullptr;
    g1.srcs.s[0] = agg_gw; g1.srcs.s[1] = xb0g;
    g1.Bt = BtBuf + 0; g1.bias = biasBuf + 0; g1.M = NGW; g1.K = 512;
    g1.outb = xb1g; g1.outf = nullptr;
    g2.srcs.s[0] = agg_hru; g2.srcs.s[1] = xb0h;
    g2.Bt = BtBuf + 393216; g2.bias = biasBuf + 512; g2.M = NHRU; g2.K = 512;
    g2.outb = xb1h; g2.outf = nullptr;
    const int nb0 = (NCH + 127) / 128;
    const int nb1 = (NGW + 127) / 128;
    const int nb2 = (NHRU + 127) / 128;
    gemm_multi3<<<dim3(nb0 + nb1 + nb2), 512, 0, stream>>>(g0, g1, g2, nb0, nb0 + nb1);
  }

  // layer 2: channel-dst relations (hyd, sw, gwsw), single dispatch
  {
    AggTab t1{};
    t1.src[1] = xb1c; t1.out[1] = agg_c0;
    t1.src[2] = xb1h; t1.out[2] = agg_c1;
    t1.src[3] = xb1g; t1.out[3] = agg_c2;
    agg_pair<<<15000, 256, 0, stream>>>(rp, ssrc, t1, 5000, 10000, 15000, 15000, 1, 2, 3, 3, 3);
  }

  // layer 2 channel GEMM -> fp32 c2
  {
    GArgs g{};
    g.srcs.s[0] = agg_c0; g.srcs.s[1] = agg_c1; g.srcs.s[2] = agg_c2; g.srcs.s[3] = xb1c;
    g.Bt = BtBuf + 524288; g.bias = biasBuf + 768; g.M = NCH; g.K = 1024;
    g.outb = nullptr; g.outf = c2f;
    gemm_bt<<<dim3((NCH + 127) / 128), 512, 0, stream>>>(g);
  }

  pool_partial<<<625, 256, 0, stream>>>(c2f, batch, pooled_sum);
  mlp_kernel<<<64, 128, 0, stream>>>(pooled_sum, batch, train, fc1w, fc1b, fc2w, fc2b, out);

  (void)in_sizes; (void)n_in; (void)out_size; (void)ws_size;
}

// Round 15
// 485.828 us; speedup vs baseline: 1.0416x; 1.0416x over previous
//
#include <hip/hip_runtime.h>

#define E_EDGES 250000
#define NHRU 100000
#define NCH  40000
#define NGW  60000
#define NCNT 280000
#define NBLK_SCAN 1094

// fused_pre block ranges (R12 form): count | cvt | prep
#define NB_E    977
#define NB_CNT  (5 * NB_E)
#define NB_CVT  25000
#define NB_PREP 3076

typedef __attribute__((ext_vector_type(4))) float f32x4;
typedef __attribute__((ext_vector_type(2))) float f32x2;
typedef __attribute__((ext_vector_type(8))) __bf16 bf16x8;
typedef __attribute__((ext_vector_type(8))) short short8;

__device__ __forceinline__ float bf2f(short h) {
  unsigned u = ((unsigned)(unsigned short)h) << 16;
  return __builtin_bit_cast(float, u);
}
__device__ __forceinline__ short f2bf(float f) {
  unsigned u = __builtin_bit_cast(unsigned, f);
  u = u + 0x7fffu + ((u >> 16) & 1u);
  return (short)(u >> 16);
}

__device__ __forceinline__ void load_lds16(const void* g, void* lds) {
  __builtin_amdgcn_global_load_lds(
      (const __attribute__((address_space(1))) unsigned*)g,
      (__attribute__((address_space(3))) unsigned*)lds, 16, 0, 0);
}

struct P5 { const int* p[5]; };

// ---------------- fused front-end: count_rank | cvt3 | prep_w (R12 form) ----------------
__global__ void fused_pre(const float* __restrict__ xh, const float* __restrict__ xc,
                          const float* __restrict__ xg, short* __restrict__ oh,
                          short* __restrict__ oc, short* __restrict__ og,
                          const float* __restrict__ Wl, const float* __restrict__ Wr,
                          const float* __restrict__ bs, short* __restrict__ Bt,
                          float* __restrict__ bias,
                          P5 dst, int* __restrict__ cnt, int* __restrict__ rank) {
  int b = blockIdx.x;
  if (b < NB_CNT) {
    // ---- count + rank ----
    const int COFF[5] = {0, 60000, 100000, 140000, 180000};
    int r = b / NB_E;
    int e = (b - r * NB_E) * 256 + threadIdx.x;
    if (e < E_EDGES) {
      int d = dst.p[r][e];
      int rk = atomicAdd(&cnt[COFF[r] + d], 1);
      rank[r * E_EDGES + e] = rk;
    }
  } else if (b < NB_CNT + NB_CVT) {
    // ---- fp32 -> bf16 convert, 32B/thread, nt loads ----
    int i = (b - NB_CNT) * 256 + threadIdx.x;   // unit = 8 floats
    const int n1 = NHRU * 32, n2 = n1 + NCH * 32;
    const float* in; short* out; int j;
    if (i < n1) { in = xh; out = oh; j = i; }
    else if (i < n2) { in = xc; out = oc; j = i - n1; }
    else { in = xg; out = og; j = i - n2; }
    const f32x4* p = reinterpret_cast<const f32x4*>(in) + (size_t)j * 2;
    f32x4 v0 = __builtin_nontemporal_load(p);
    f32x4 v1 = __builtin_nontemporal_load(p + 1);
    short8 o;
#pragma unroll
    for (int k = 0; k < 4; ++k) { o[k] = f2bf(v0[k]); o[4 + k] = f2bf(v1[k]); }
    reinterpret_cast<short8*>(out)[j] = o;
  } else {
    // ---- weight prep: transpose + bf16 + fold /3 ----
    int i = (b - NB_CNT - NB_CVT) * 256 + threadIdx.x;
    const float inv3 = 1.0f / 3.0f;
    if (i < 131072) {                       // gw: l=0,r=0
      int n = i >> 9, k = i & 511;
      float v = (k < 256) ? Wl[(0 * 256 + k) * 256 + n]
                          : Wr[(0 * 256 + (k - 256)) * 256 + n];
      Bt[i] = f2bf(v);
    } else if (i < 393216) {                // ch l=0
      int j = i - 131072;
      int n = j >> 10, k = j & 1023;
      float v;
      if (k < 768) {
        int r = 1 + (k >> 8), kk = k & 255;
        v = Wl[((0 * 5 + r) * 256 + kk) * 256 + n] * inv3;
      } else {
        int kk = k - 768;
        v = (Wr[((0 * 5 + 1) * 256 + kk) * 256 + n] +
             Wr[((0 * 5 + 2) * 256 + kk) * 256 + n] +
             Wr[((0 * 5 + 3) * 256 + kk) * 256 + n]) * inv3;
      }
      Bt[i] = f2bf(v);
    } else if (i < 524288) {                // hru: l=0,r=4
      int j = i - 393216;
      int n = j >> 9, k = j & 511;
      float v = (k < 256) ? Wl[((0 * 5 + 4) * 256 + k) * 256 + n]
                          : Wr[((0 * 5 + 4) * 256 + (k - 256)) * 256 + n];
      Bt[i] = f2bf(v);
    } else if (i < 786432) {                // ch l=1
      int j = i - 524288;
      int n = j >> 10, k = j & 1023;
      float v;
      if (k < 768) {
        int r = 1 + (k >> 8), kk = k & 255;
        v = Wl[((5 + r) * 256 + kk) * 256 + n] * inv3;
      } else {
        int kk = k - 768;
        v = (Wr[((5 + 1) * 256 + kk) * 256 + n] +
             Wr[((5 + 2) * 256 + kk) * 256 + n] +
             Wr[((5 + 3) * 256 + kk) * 256 + n]) * inv3;
      }
      Bt[i] = f2bf(v);
    } else if (i < 787456) {                // biases
      int j = i - 786432;
      int g = j >> 8, n = j & 255;
      float v;
      if (g == 0)      v = bs[n];
      else if (g == 1) v = (bs[256 + n] + bs[512 + n] + bs[768 + n]) * inv3;
      else if (g == 2) v = bs[1024 + n];
      else             v = (bs[1280 + 256 + n] + bs[1280 + 512 + n] + bs[1280 + 768 + n]) * inv3;
      bias[j] = v;
    }
  }
}

// ---------------- global scan (3 kernels) ----------------
__global__ void scan_a(const int* __restrict__ cnt, int* __restrict__ bsum) {
  int i = blockIdx.x * 256 + threadIdx.x;
  int v = (i < NCNT) ? cnt[i] : 0;
  int lane = threadIdx.x & 63, wv = threadIdx.x >> 6;
  for (int d = 1; d < 64; d <<= 1) v += __shfl_down(v, d);
  __shared__ int ws[4];
  if (lane == 0) ws[wv] = v;
  __syncthreads();
  if (threadIdx.x == 0) bsum[blockIdx.x] = ws[0] + ws[1] + ws[2] + ws[3];
}

__global__ void scan_b(const int* __restrict__ bsum, int* __restrict__ boff) {
  int t = threadIdx.x;
  int e0 = 2 * t, e1 = 2 * t + 1;
  int v0 = (e0 < NBLK_SCAN) ? bsum[e0] : 0;
  int v1 = (e1 < NBLK_SCAN) ? bsum[e1] : 0;
  __shared__ int lds[1024];
  lds[t] = v0 + v1;
  __syncthreads();
  for (int o = 1; o < 1024; o <<= 1) {
    int add = (t >= o) ? lds[t - o] : 0;
    __syncthreads();
    lds[t] += add;
    __syncthreads();
  }
  int ex = (t == 0) ? 0 : lds[t - 1];
  if (e0 < NBLK_SCAN) boff[e0] = ex;
  if (e1 < NBLK_SCAN) boff[e1] = ex + v0;
}

__global__ void scan_c(const int* __restrict__ cnt, const int* __restrict__ boff,
                       int* __restrict__ S) {
  int i = blockIdx.x * 256 + threadIdx.x;
  int v = (i < NCNT) ? cnt[i] : 0;
  int lane = threadIdx.x & 63, wv = threadIdx.x >> 6;
  int inc = v;
  for (int d = 1; d < 64; d <<= 1) {
    int y = __shfl_up(inc, d);
    if (lane >= d) inc += y;
  }
  __shared__ int ws[4];
  if (lane == 63) ws[wv] = inc;
  __syncthreads();
  int wex = 0;
  for (int k = 0; k < 4; ++k) wex += (k < wv) ? ws[k] : 0;
  int ex = boff[blockIdx.x] + wex + inc - v;
  if (i < NCNT) S[i] = ex;
  if (blockIdx.x == 0 && threadIdx.x == 0) S[NCNT] = 5 * E_EDGES;
}

// pass 2: scatter without atomics
__global__ void scatter_kernel(P5 src, P5 dst, const int* __restrict__ rp,
                               const int* __restrict__ rank, int* __restrict__ ssrc) {
  const int COFF[5] = {0, 60000, 100000, 140000, 180000};
  int r = blockIdx.y;
  int e = blockIdx.x * blockDim.x + threadIdx.x;
  if (e < E_EDGES) {
    int d = dst.p[r][e];
    int idx = rp[COFF[r] + d] + rank[r * E_EDGES + e];
    ssrc[idx] = src.p[r][e];
  }
}

// ---------------- paired mean aggregation: 2 items/wave, 2 gather chains per half ----------------
struct AggTab { const short* src[5]; short* out[5]; };

__global__ void agg_pair(const int* __restrict__ rp, const int* __restrict__ ssrc,
                         AggTab tab, int be0, int be1, int be2, int be3,
                         int r0, int r1, int r2, int r3, int r4) {
  int b = blockIdx.x;
  int r, b0;
  if (b < be0)      { r = r0; b0 = 0; }
  else if (b < be1) { r = r1; b0 = be0; }
  else if (b < be2) { r = r2; b0 = be1; }
  else if (b < be3) { r = r3; b0 = be2; }
  else              { r = r4; b0 = be3; }
  int coff = r == 0 ? 0 : r == 1 ? 60000 : r == 2 ? 100000 : r == 3 ? 140000 : 180000;
  int nrel = r == 0 ? 60000 : r == 4 ? 100000 : 40000;
  const short* xs = r == 0 ? tab.src[0] : r == 1 ? tab.src[1] : r == 2 ? tab.src[2]
                   : r == 3 ? tab.src[3] : tab.src[4];
  short* ob = r == 0 ? tab.out[0] : r == 1 ? tab.out[1] : r == 2 ? tab.out[2]
             : r == 3 ? tab.out[3] : tab.out[4];

  int wid = threadIdx.x >> 6;
  int lane = threadIdx.x & 63;
  int half = lane >> 5, l32 = lane & 31;
  int row = (b - b0) * 8 + wid * 2 + half;
  bool active = row < nrel;
  int item = coff + row;
  int lo = 0, hi = 0;
  if (active) { lo = rp[item]; hi = rp[item + 1]; }

  f32x2 a0[4], a1[4];
#pragma unroll
  for (int k = 0; k < 4; ++k) { a0[k] = (f32x2){0.f, 0.f}; a1[k] = (f32x2){0.f, 0.f}; }
  int e = lo;
  for (; e + 1 < hi; e += 2) {
    int s0 = ssrc[e];
    int s1 = ssrc[e + 1];
    uint4 u0 = *reinterpret_cast<const uint4*>(xs + (size_t)s0 * 256 + l32 * 8);
    uint4 u1 = *reinterpret_cast<const uint4*>(xs + (size_t)s1 * 256 + l32 * 8);
    unsigned d0[4] = {u0.x, u0.y, u0.z, u0.w};
    unsigned d1[4] = {u1.x, u1.y, u1.z, u1.w};
#pragma unroll
    for (int k = 0; k < 4; ++k) {
      a0[k] += (f32x2){__builtin_bit_cast(float, d0[k] << 16),
                       __builtin_bit_cast(float, d0[k] & 0xffff0000u)};
      a1[k] += (f32x2){__builtin_bit_cast(float, d1[k] << 16),
                       __builtin_bit_cast(float, d1[k] & 0xffff0000u)};
    }
  }
  if (e < hi) {
    int s = ssrc[e];
    uint4 u = *reinterpret_cast<const uint4*>(xs + (size_t)s * 256 + l32 * 8);
    unsigned d[4] = {u.x, u.y, u.z, u.w};
#pragma unroll
    for (int k = 0; k < 4; ++k) {
      a0[k] += (f32x2){__builtin_bit_cast(float, d[k] << 16),
                       __builtin_bit_cast(float, d[k] & 0xffff0000u)};
    }
  }
#pragma unroll
  for (int k = 0; k < 4; ++k) a0[k] += a1[k];
  if (active) {
    int c = hi - lo; if (c < 1) c = 1;
    float inv = 1.0f / (float)c;
    short8 o;
#pragma unroll
    for (int k = 0; k < 4; ++k) {
      o[2 * k] = f2bf(a0[k].x * inv);
      o[2 * k + 1] = f2bf(a0[k].y * inv);
    }
    *reinterpret_cast<short8*>(ob + (size_t)row * 256 + l32 * 8) = o;
  }
}

// ---------------- bf16 MFMA GEMM: BM=128, BN=256, BK=32, 2-phase dbuf pipeline ----------------
// LDS (shorts): A0 @0 (4096), B0 @4096 (8192), A1 @12288 (4096), B1 @16384 (8192) = 48KB.
// Per tile: prefetch(t+1) issued BEFORE compute(t); single __syncthreads()/tile
// (its implicit vmcnt-drain lands after the MFMAs -> load latency hides under compute).
struct Srcs4 { const short* s[4]; };
struct GArgs {
  Srcs4 srcs; const short* Bt; const float* bias;
  int M; int K; short* outb; float* outf;
};

__device__ __forceinline__ void gemm_stage(const GArgs& a, short* sm, int m0,
                                           int k0, int sel, int w, int lane) {
  short* Abuf = sm + sel * 12288;
  short* Bbuf = sm + sel * 12288 + 4096;
  const short* Aq = a.srcs.s[k0 >> 8];
  const int kc = k0 & 255;
  const int M = a.M;
  {
    const int rbase = w * 16;
    const int row = rbase + (lane >> 2);
    const int cs = ((lane & 3) ^ (row & 3)) << 3;   // pre-swizzled source chunk (shorts)
    int gr = m0 + row; gr = gr < M ? gr : M - 1;
    load_lds16(Aq + (size_t)gr * 256 + kc + cs, &Abuf[rbase * 32]);
  }
#pragma unroll
  for (int rr = 0; rr < 2; ++rr) {
    const int rbase = w * 32 + rr * 16;
    const int row = rbase + (lane >> 2);
    const int cs = ((lane & 3) ^ (row & 3)) << 3;
    load_lds16(a.Bt + (size_t)row * a.K + k0 + cs, &Bbuf[rbase * 32]);
  }
}

__device__ __forceinline__ void gemm_body(const GArgs& a, int bx) {
  __shared__ short sm[24576];
  const int tid = threadIdx.x;
  const int lane = tid & 63;
  const int w = tid >> 6;             // 0..7
  const int wr = w >> 2, wc = w & 3;  // 2 x 4 wave grid
  const int m0 = bx * 128;
  const int M = a.M, K = a.K;

  f32x4 acc[4][4];
#pragma unroll
  for (int i = 0; i < 4; ++i)
#pragma unroll
    for (int j = 0; j < 4; ++j) acc[i][j] = (f32x4){0.f, 0.f, 0.f, 0.f};

  const int nt = K >> 5;
  gemm_stage(a, sm, m0, 0, 0, w, lane);
  __syncthreads();
  int sel = 0;
  for (int t = 0; t < nt; ++t) {
    if (t + 1 < nt) gemm_stage(a, sm, m0, (t + 1) << 5, sel ^ 1, w, lane);
    {
      const short* Abuf = sm + sel * 12288;
      const short* Bbuf = sm + sel * 12288 + 4096;
      const int cg = lane >> 4;                      // k-chunk 0..3
      bf16x8 af[4], bfr[4];
#pragma unroll
      for (int mi = 0; mi < 4; ++mi) {
        const int r = wr * 64 + mi * 16 + (lane & 15);
        af[mi] = *reinterpret_cast<const bf16x8*>(&Abuf[r * 32 + ((cg ^ (r & 3)) << 3)]);
      }
#pragma unroll
      for (int nj = 0; nj < 4; ++nj) {
        const int r = wc * 64 + nj * 16 + (lane & 15);
        bfr[nj] = *reinterpret_cast<const bf16x8*>(&Bbuf[r * 32 + ((cg ^ (r & 3)) << 3)]);
      }
#pragma unroll
      for (int mi = 0; mi < 4; ++mi)
#pragma unroll
        for (int nj = 0; nj < 4; ++nj)
          acc[mi][nj] = __builtin_amdgcn_mfma_f32_16x16x32_bf16(af[mi], bfr[nj], acc[mi][nj], 0, 0, 0);
    }
    __syncthreads();   // drains prefetch loads (vmcnt) + protects buffer reuse
    sel ^= 1;
  }

  const int rb = (lane >> 4) << 2;
  const int cl = lane & 15;

  if (a.outb) {
#pragma unroll
    for (int halfp = 0; halfp < 2; ++halfp) {
      __syncthreads();
      if (wr == halfp) {
#pragma unroll
        for (int mi = 0; mi < 4; ++mi)
#pragma unroll
          for (int nj = 0; nj < 4; ++nj) {
            const int col = wc * 64 + nj * 16 + cl;
            const float bv = a.bias[col];
#pragma unroll
            for (int j = 0; j < 4; ++j) {
              const int rloc = mi * 16 + rb + j;
              float v = fmaxf(acc[mi][nj][j] + bv, 0.0f);
              sm[rloc * 264 + col] = f2bf(v);
            }
          }
      }
      __syncthreads();
#pragma unroll
      for (int q = 0; q < 4; ++q) {
        int c = q * 512 + tid;
        int rloc = c >> 5;
        int coff = (c & 31) * 8;
        int grow = m0 + halfp * 64 + rloc;
        if (grow < M) {
          short8 vv = *reinterpret_cast<const short8*>(&sm[rloc * 264 + coff]);
          *reinterpret_cast<short8*>(a.outb + (size_t)grow * 256 + coff) = vv;
        }
      }
    }
  }
  if (a.outf) {
    float* fsm = reinterpret_cast<float*>(sm);
#pragma unroll
    for (int p = 0; p < 4; ++p) {
      __syncthreads();
      if (wr == (p >> 1)) {
#pragma unroll
        for (int mm = 0; mm < 2; ++mm) {
          const int mi = (p & 1) * 2 + mm;
#pragma unroll
          for (int nj = 0; nj < 4; ++nj) {
            const int col = wc * 64 + nj * 16 + cl;
            const float bv = a.bias[col];
#pragma unroll
            for (int j = 0; j < 4; ++j) {
              const int rloc = mi * 16 + rb + j - (p & 1) * 32;
              float v = fmaxf(acc[mi][nj][j] + bv, 0.0f);
              fsm[rloc * 260 + col] = v;
            }
          }
        }
      }
      __syncthreads();
#pragma unroll
      for (int q = 0; q < 4; ++q) {
        int c = q * 512 + tid;
        int rloc = c >> 6;
        int coff = (c & 63) * 4;
        int grow = m0 + p * 32 + rloc;
        if (grow < M) {
          float4 vv = *reinterpret_cast<const float4*>(&fsm[rloc * 260 + coff]);
          *reinterpret_cast<float4*>(a.outf + (size_t)grow * 256 + coff) = vv;
        }
      }
    }
  }
}

__global__ __launch_bounds__(512) void gemm_bt(GArgs a) {
  gemm_body(a, blockIdx.x);
}

__global__ __launch_bounds__(512) void gemm_multi3(GArgs a0, GArgs a1, GArgs a2,
                                                   int nb0, int nb01) {
  int bx = blockIdx.x;
  if (bx < nb0) gemm_body(a0, bx);
  else if (bx < nb01) gemm_body(a1, bx - nb0);
  else gemm_body(a2, bx - nb01);
}

// ---------------- pooling (two-stage) + MLP ----------------
__device__ __forceinline__ int lower_bound(const int* a, int n, int v) {
  int lo = 0, hi = n;
  while (lo < hi) { int mid = (lo + hi) >> 1; if (a[mid] < v) lo = mid + 1; else hi = mid; }
  return lo;
}

__global__ void pool_partial(const float* __restrict__ c2, const int* __restrict__ batch,
                             float* __restrict__ pooled_sum) {
  int r0 = blockIdx.x * 64;
  int t = threadIdx.x;
  float acc = 0.f;
  int prevb = batch[r0];
  for (int i = 0; i < 64; ++i) {
    int r = r0 + i;
    int b = batch[r];
    if (b != prevb) {
      atomicAdd(&pooled_sum[prevb * 256 + t], acc);
      acc = 0.f; prevb = b;
    }
    acc += c2[(size_t)r * 256 + t];
  }
  atomicAdd(&pooled_sum[prevb * 256 + t], acc);
}

__global__ void mlp_kernel(const float* __restrict__ pooled_sum, const int* __restrict__ batch,
                           const float* __restrict__ train,
                           const float* __restrict__ fc1w, const float* __restrict__ fc1b,
                           const float* __restrict__ fc2w, const float* __restrict__ fc2b,
                           float* __restrict__ out) {
  int b = blockIdx.x, t = threadIdx.x;
  __shared__ float x[288];
  __shared__ float hsm[128];
  __shared__ float sinv;
  if (t == 0) {
    int lo = lower_bound(batch, NCH, b);
    int hi = lower_bound(batch, NCH, b + 1);
    int c = hi - lo; if (c < 1) c = 1;
    sinv = 1.0f / (float)c;
  }
  __syncthreads();
  float inv = sinv;
  x[t] = pooled_sum[b * 256 + t] * inv;
  x[128 + t] = pooled_sum[b * 256 + 128 + t] * inv;
  if (t < 32) x[256 + t] = train[b * 32 + t];
  __syncthreads();
  float s = fc1b[t];
  for (int i = 0; i < 288; ++i) s += x[i] * fc1w[i * 128 + t];
  hsm[t] = fmaxf(s, 0.f);
  __syncthreads();
  if (t < 16) {
    float o = fc2b[t];
    for (int i = 0; i < 128; ++i) o += hsm[i] * fc2w[i * 16 + t];
    out[b * 16 + t] = o;
  }
}

// ---------------- launch ----------------
extern "C" void kernel_launch(void* const* d_in, const int* in_sizes, int n_in,
                              void* d_out, int out_size, void* d_ws, size_t ws_size,
                              hipStream_t stream) {
  const float* x_hru = (const float*)d_in[0];
  const float* x_ch  = (const float*)d_in[1];
  const float* x_gw  = (const float*)d_in[2];
  const int* src_swgw = (const int*)d_in[3];
  const int* dst_swgw = (const int*)d_in[4];
  const int* src_hyd  = (const int*)d_in[5];
  const int* dst_hyd  = (const int*)d_in[6];
  const int* src_sw   = (const int*)d_in[7];
  const int* dst_sw   = (const int*)d_in[8];
  const int* src_gwsw = (const int*)d_in[9];
  const int* dst_gwsw = (const int*)d_in[10];
  const int* src_slf  = (const int*)d_in[11];
  const int* dst_slf  = (const int*)d_in[12];
  const int* batch    = (const int*)d_in[13];
  const float* train  = (const float*)d_in[14];
  const float* Wl     = (const float*)d_in[15];
  const float* Wr     = (const float*)d_in[16];
  const float* bs     = (const float*)d_in[17];
  const float* fc1w   = (const float*)d_in[18];
  const float* fc1b   = (const float*)d_in[19];
  const float* fc2w   = (const float*)d_in[20];
  const float* fc2b   = (const float*)d_in[21];
  float* out = (float*)d_out;

  char* ws = (char*)d_ws;
  size_t off = 0;
  auto alloc = [&](size_t bytes) -> void* {
    off = (off + 255) & ~(size_t)255;
    void* p = ws + off;
    off += bytes;
    return p;
  };

  short* xb0h = (short*)alloc((size_t)NHRU * 256 * 2);
  short* xb0c = (short*)alloc((size_t)NCH * 256 * 2);
  short* xb0g = (short*)alloc((size_t)NGW * 256 * 2);
  short* xb1h = (short*)alloc((size_t)NHRU * 256 * 2);
  short* xb1c = (short*)alloc((size_t)NCH * 256 * 2);
  short* xb1g = (short*)alloc((size_t)NGW * 256 * 2);
  short* agg_gw  = (short*)alloc((size_t)NGW * 256 * 2);
  short* agg_c0  = (short*)alloc((size_t)NCH * 256 * 2);
  short* agg_c1  = (short*)alloc((size_t)NCH * 256 * 2);
  short* agg_c2  = (short*)alloc((size_t)NCH * 256 * 2);
  short* agg_hru = (short*)alloc((size_t)NHRU * 256 * 2);
  float* c2f = (float*)alloc((size_t)NCH * 256 * 4);
  int* cnt  = (int*)alloc(NCNT * 4);
  int* rp   = (int*)alloc((NCNT + 1) * 4);
  int* rank = (int*)alloc((size_t)5 * E_EDGES * 4);
  int* bsum = (int*)alloc(NBLK_SCAN * 4);
  int* boff = (int*)alloc(NBLK_SCAN * 4);
  int* ssrc = (int*)alloc((size_t)5 * E_EDGES * 4);
  short* BtBuf = (short*)alloc(786432 * 2);
  float* biasBuf = (float*)alloc(1024 * 4);
  float* pooled_sum = (float*)alloc(64 * 256 * 4);

  hipMemsetAsync(cnt, 0, NCNT * 4, stream);
  hipMemsetAsync(pooled_sum, 0, 64 * 256 * 4, stream);

  P5 dsts; dsts.p[0] = dst_swgw; dsts.p[1] = dst_hyd; dsts.p[2] = dst_sw;
  dsts.p[3] = dst_gwsw; dsts.p[4] = dst_slf;
  P5 srcs; srcs.p[0] = src_swgw; srcs.p[1] = src_hyd; srcs.p[2] = src_sw;
  srcs.p[3] = src_gwsw; srcs.p[4] = src_slf;

  // fused front-end: count_rank | cvt | prep_w (R12 form)
  fused_pre<<<NB_CNT + NB_CVT + NB_PREP, 256, 0, stream>>>(
      x_hru, x_ch, x_gw, xb0h, xb0c, xb0g,
      Wl, Wr, bs, BtBuf, biasBuf, dsts, cnt, rank);

  scan_a<<<NBLK_SCAN, 256, 0, stream>>>(cnt, bsum);
  scan_b<<<1, 1024, 0, stream>>>(bsum, boff);
  scan_c<<<NBLK_SCAN, 256, 0, stream>>>(cnt, boff, rp);
  dim3 eg(NB_E, 5);
  scatter_kernel<<<eg, 256, 0, stream>>>(srcs, dsts, rp, rank, ssrc);

  // layer 1: all 5 relations, single dispatch
  {
    AggTab t0{};
    t0.src[0] = xb0h; t0.out[0] = agg_gw;
    t0.src[1] = xb0c; t0.out[1] = agg_c0;
    t0.src[2] = xb0h; t0.out[2] = agg_c1;
    t0.src[3] = xb0g; t0.out[3] = agg_c2;
    t0.src[4] = xb0h; t0.out[4] = agg_hru;
    agg_pair<<<35000, 256, 0, stream>>>(rp, ssrc, t0, 7500, 12500, 17500, 22500, 0, 1, 2, 3, 4);
  }

  // layer 1 GEMMs (merged, ch-first: ch | gw | hru)
  {
    GArgs g0{}, g1{}, g2{};
    g0.srcs.s[0] = agg_c0; g0.srcs.s[1] = agg_c1; g0.srcs.s[2] = agg_c2; g0.srcs.s[3] = xb0c;
    g0.Bt = BtBuf + 131072; g0.bias = biasBuf + 256; g0.M = NCH; g0.K = 1024;
    g0.outb = xb1c; g0.outf = nullptr;
    g1.srcs.s[0] = agg_gw; g1.srcs.s[1] = xb0g;
    g1.Bt = BtBuf + 0; g1.bias = biasBuf + 0; g1.M = NGW; g1.K = 512;
    g1.outb = xb1g; g1.outf = nullptr;
    g2.srcs.s[0] = agg_hru; g2.srcs.s[1] = xb0h;
    g2.Bt = BtBuf + 393216; g2.bias = biasBuf + 512; g2.M = NHRU; g2.K = 512;
    g2.outb = xb1h; g2.outf = nullptr;
    const int nb0 = (NCH + 127) / 128;
    const int nb1 = (NGW + 127) / 128;
    const int nb2 = (NHRU + 127) / 128;
    gemm_multi3<<<dim3(nb0 + nb1 + nb2), 512, 0, stream>>>(g0, g1, g2, nb0, nb0 + nb1);
  }

  // layer 2: channel-dst relations (hyd, sw, gwsw), single dispatch
  {
    AggTab t1{};
    t1.src[1] = xb1c; t1.out[1] = agg_c0;
    t1.src[2] = xb1h; t1.out[2] = agg_c1;
    t1.src[3] = xb1g; t1.out[3] = agg_c2;
    agg_pair<<<15000, 256, 0, stream>>>(rp, ssrc, t1, 5000, 10000, 15000, 15000, 1, 2, 3, 3, 3);
  }

  // layer 2 channel GEMM -> fp32 c2
  {
    GArgs g{};
    g.srcs.s[0] = agg_c0; g.srcs.s[1] = agg_c1; g.srcs.s[2] = agg_c2; g.srcs.s[3] = xb1c;
    g.Bt = BtBuf + 524288; g.bias = biasBuf + 768; g.M = NCH; g.K = 1024;
    g.outb = nullptr; g.outf = c2f;
    gemm_bt<<<dim3((NCH + 127) / 128), 512, 0, stream>>>(g);
  }

  pool_partial<<<625, 256, 0, stream>>>(c2f, batch, pooled_sum);
  mlp_kernel<<<64, 128, 0, stream>>>(pooled_sum, batch, train, fc1w, fc1b, fc2w, fc2b, out);

  (void)in_sizes; (void)n_in; (void)out_size; (void)ws_size;
}

// Round 16
// 483.563 us; speedup vs baseline: 1.0465x; 1.0047x over previous
//
#include <hip/hip_runtime.h>

#define E_EDGES 250000
#define NHRU 100000
#define NCH  40000
#define NGW  60000
#define NCNT 280000
#define NBLK_SCAN 1094

// fused_pre block ranges (R12 form): count | cvt | prep
#define NB_E    977
#define NB_CNT  (5 * NB_E)
#define NB_CVT  25000
#define NB_PREP 3076

typedef __attribute__((ext_vector_type(4))) float f32x4;
typedef __attribute__((ext_vector_type(2))) float f32x2;
typedef __attribute__((ext_vector_type(8))) __bf16 bf16x8;
typedef __attribute__((ext_vector_type(8))) short short8;

__device__ __forceinline__ float bf2f(short h) {
  unsigned u = ((unsigned)(unsigned short)h) << 16;
  return __builtin_bit_cast(float, u);
}
__device__ __forceinline__ short f2bf(float f) {
  unsigned u = __builtin_bit_cast(unsigned, f);
  u = u + 0x7fffu + ((u >> 16) & 1u);
  return (short)(u >> 16);
}

__device__ __forceinline__ void load_lds16(const void* g, void* lds) {
  __builtin_amdgcn_global_load_lds(
      (const __attribute__((address_space(1))) unsigned*)g,
      (__attribute__((address_space(3))) unsigned*)lds, 16, 0, 0);
}

struct P5 { const int* p[5]; };

// ---------------- fused front-end: count_rank | cvt3 | prep_w ----------------
__global__ void fused_pre(const float* __restrict__ xh, const float* __restrict__ xc,
                          const float* __restrict__ xg, short* __restrict__ oh,
                          short* __restrict__ oc, short* __restrict__ og,
                          const float* __restrict__ Wl, const float* __restrict__ Wr,
                          const float* __restrict__ bs, short* __restrict__ Bt,
                          float* __restrict__ bias,
                          P5 dst, int* __restrict__ cnt, int* __restrict__ rank) {
  int b = blockIdx.x;
  if (b < NB_CNT) {
    // ---- count + rank ----
    const int COFF[5] = {0, 60000, 100000, 140000, 180000};
    int r = b / NB_E;
    int e = (b - r * NB_E) * 256 + threadIdx.x;
    if (e < E_EDGES) {
      int d = dst.p[r][e];
      int rk = atomicAdd(&cnt[COFF[r] + d], 1);
      rank[r * E_EDGES + e] = rk;
    }
  } else if (b < NB_CNT + NB_CVT) {
    // ---- fp32 -> bf16 convert, 32B/thread, nt loads ----
    int i = (b - NB_CNT) * 256 + threadIdx.x;   // unit = 8 floats
    const int n1 = NHRU * 32, n2 = n1 + NCH * 32;
    const float* in; short* out; int j;
    if (i < n1) { in = xh; out = oh; j = i; }
    else if (i < n2) { in = xc; out = oc; j = i - n1; }
    else { in = xg; out = og; j = i - n2; }
    const f32x4* p = reinterpret_cast<const f32x4*>(in) + (size_t)j * 2;
    f32x4 v0 = __builtin_nontemporal_load(p);
    f32x4 v1 = __builtin_nontemporal_load(p + 1);
    short8 o;
#pragma unroll
    for (int k = 0; k < 4; ++k) { o[k] = f2bf(v0[k]); o[4 + k] = f2bf(v1[k]); }
    reinterpret_cast<short8*>(out)[j] = o;
  } else {
    // ---- weight prep: transpose + bf16 + fold /3 ----
    int i = (b - NB_CNT - NB_CVT) * 256 + threadIdx.x;
    const float inv3 = 1.0f / 3.0f;
    if (i < 131072) {                       // gw: l=0,r=0
      int n = i >> 9, k = i & 511;
      float v = (k < 256) ? Wl[(0 * 256 + k) * 256 + n]
                          : Wr[(0 * 256 + (k - 256)) * 256 + n];
      Bt[i] = f2bf(v);
    } else if (i < 393216) {                // ch l=0
      int j = i - 131072;
      int n = j >> 10, k = j & 1023;
      float v;
      if (k < 768) {
        int r = 1 + (k >> 8), kk = k & 255;
        v = Wl[((0 * 5 + r) * 256 + kk) * 256 + n] * inv3;
      } else {
        int kk = k - 768;
        v = (Wr[((0 * 5 + 1) * 256 + kk) * 256 + n] +
             Wr[((0 * 5 + 2) * 256 + kk) * 256 + n] +
             Wr[((0 * 5 + 3) * 256 + kk) * 256 + n]) * inv3;
      }
      Bt[i] = f2bf(v);
    } else if (i < 524288) {                // hru: l=0,r=4
      int j = i - 393216;
      int n = j >> 9, k = j & 511;
      float v = (k < 256) ? Wl[((0 * 5 + 4) * 256 + k) * 256 + n]
                          : Wr[((0 * 5 + 4) * 256 + (k - 256)) * 256 + n];
      Bt[i] = f2bf(v);
    } else if (i < 786432) {                // ch l=1
      int j = i - 524288;
      int n = j >> 10, k = j & 1023;
      float v;
      if (k < 768) {
        int r = 1 + (k >> 8), kk = k & 255;
        v = Wl[((5 + r) * 256 + kk) * 256 + n] * inv3;
      } else {
        int kk = k - 768;
        v = (Wr[((5 + 1) * 256 + kk) * 256 + n] +
             Wr[((5 + 2) * 256 + kk) * 256 + n] +
             Wr[((5 + 3) * 256 + kk) * 256 + n]) * inv3;
      }
      Bt[i] = f2bf(v);
    } else if (i < 787456) {                // biases
      int j = i - 786432;
      int g = j >> 8, n = j & 255;
      float v;
      if (g == 0)      v = bs[n];
      else if (g == 1) v = (bs[256 + n] + bs[512 + n] + bs[768 + n]) * inv3;
      else if (g == 2) v = bs[1024 + n];
      else             v = (bs[1280 + 256 + n] + bs[1280 + 512 + n] + bs[1280 + 768 + n]) * inv3;
      bias[j] = v;
    }
  }
}

// ---------------- global scan (3 kernels) ----------------
__global__ void scan_a(const int* __restrict__ cnt, int* __restrict__ bsum) {
  int i = blockIdx.x * 256 + threadIdx.x;
  int v = (i < NCNT) ? cnt[i] : 0;
  int lane = threadIdx.x & 63, wv = threadIdx.x >> 6;
  for (int d = 1; d < 64; d <<= 1) v += __shfl_down(v, d);
  __shared__ int ws[4];
  if (lane == 0) ws[wv] = v;
  __syncthreads();
  if (threadIdx.x == 0) bsum[blockIdx.x] = ws[0] + ws[1] + ws[2] + ws[3];
}

__global__ void scan_b(const int* __restrict__ bsum, int* __restrict__ boff) {
  int t = threadIdx.x;
  int e0 = 2 * t, e1 = 2 * t + 1;
  int v0 = (e0 < NBLK_SCAN) ? bsum[e0] : 0;
  int v1 = (e1 < NBLK_SCAN) ? bsum[e1] : 0;
  __shared__ int lds[1024];
  lds[t] = v0 + v1;
  __syncthreads();
  for (int o = 1; o < 1024; o <<= 1) {
    int add = (t >= o) ? lds[t - o] : 0;
    __syncthreads();
    lds[t] += add;
    __syncthreads();
  }
  int ex = (t == 0) ? 0 : lds[t - 1];
  if (e0 < NBLK_SCAN) boff[e0] = ex;
  if (e1 < NBLK_SCAN) boff[e1] = ex + v0;
}

__global__ void scan_c(const int* __restrict__ cnt, const int* __restrict__ boff,
                       int* __restrict__ S) {
  int i = blockIdx.x * 256 + threadIdx.x;
  int v = (i < NCNT) ? cnt[i] : 0;
  int lane = threadIdx.x & 63, wv = threadIdx.x >> 6;
  int inc = v;
  for (int d = 1; d < 64; d <<= 1) {
    int y = __shfl_up(inc, d);
    if (lane >= d) inc += y;
  }
  __shared__ int ws[4];
  if (lane == 63) ws[wv] = inc;
  __syncthreads();
  int wex = 0;
  for (int k = 0; k < 4; ++k) wex += (k < wv) ? ws[k] : 0;
  int ex = boff[blockIdx.x] + wex + inc - v;
  if (i < NCNT) S[i] = ex;
  if (blockIdx.x == 0 && threadIdx.x == 0) S[NCNT] = 5 * E_EDGES;
}

// pass 2: scatter without atomics
__global__ void scatter_kernel(P5 src, P5 dst, const int* __restrict__ rp,
                               const int* __restrict__ rank, int* __restrict__ ssrc) {
  const int COFF[5] = {0, 60000, 100000, 140000, 180000};
  int r = blockIdx.y;
  int e = blockIdx.x * blockDim.x + threadIdx.x;
  if (e < E_EDGES) {
    int d = dst.p[r][e];
    int idx = rp[COFF[r] + d] + rank[r * E_EDGES + e];
    ssrc[idx] = src.p[r][e];
  }
}

// ---------------- paired mean aggregation: 2 items/wave, 2 gather chains per half ----------------
struct AggTab { const short* src[5]; short* out[5]; };

__global__ void agg_pair(const int* __restrict__ rp, const int* __restrict__ ssrc,
                         AggTab tab, int be0, int be1, int be2, int be3,
                         int r0, int r1, int r2, int r3, int r4) {
  int b = blockIdx.x;
  int r, b0;
  if (b < be0)      { r = r0; b0 = 0; }
  else if (b < be1) { r = r1; b0 = be0; }
  else if (b < be2) { r = r2; b0 = be1; }
  else if (b < be3) { r = r3; b0 = be2; }
  else              { r = r4; b0 = be3; }
  int coff = r == 0 ? 0 : r == 1 ? 60000 : r == 2 ? 100000 : r == 3 ? 140000 : 180000;
  int nrel = r == 0 ? 60000 : r == 4 ? 100000 : 40000;
  const short* xs = r == 0 ? tab.src[0] : r == 1 ? tab.src[1] : r == 2 ? tab.src[2]
                   : r == 3 ? tab.src[3] : tab.src[4];
  short* ob = r == 0 ? tab.out[0] : r == 1 ? tab.out[1] : r == 2 ? tab.out[2]
             : r == 3 ? tab.out[3] : tab.out[4];

  int wid = threadIdx.x >> 6;
  int lane = threadIdx.x & 63;
  int half = lane >> 5, l32 = lane & 31;
  int row = (b - b0) * 8 + wid * 2 + half;
  bool active = row < nrel;
  int item = coff + row;
  int lo = 0, hi = 0;
  if (active) { lo = rp[item]; hi = rp[item + 1]; }

  f32x2 a0[4], a1[4];
#pragma unroll
  for (int k = 0; k < 4; ++k) { a0[k] = (f32x2){0.f, 0.f}; a1[k] = (f32x2){0.f, 0.f}; }
  int e = lo;
  for (; e + 1 < hi; e += 2) {
    int s0 = ssrc[e];
    int s1 = ssrc[e + 1];
    uint4 u0 = *reinterpret_cast<const uint4*>(xs + (size_t)s0 * 256 + l32 * 8);
    uint4 u1 = *reinterpret_cast<const uint4*>(xs + (size_t)s1 * 256 + l32 * 8);
    unsigned d0[4] = {u0.x, u0.y, u0.z, u0.w};
    unsigned d1[4] = {u1.x, u1.y, u1.z, u1.w};
#pragma unroll
    for (int k = 0; k < 4; ++k) {
      a0[k] += (f32x2){__builtin_bit_cast(float, d0[k] << 16),
                       __builtin_bit_cast(float, d0[k] & 0xffff0000u)};
      a1[k] += (f32x2){__builtin_bit_cast(float, d1[k] << 16),
                       __builtin_bit_cast(float, d1[k] & 0xffff0000u)};
    }
  }
  if (e < hi) {
    int s = ssrc[e];
    uint4 u = *reinterpret_cast<const uint4*>(xs + (size_t)s * 256 + l32 * 8);
    unsigned d[4] = {u.x, u.y, u.z, u.w};
#pragma unroll
    for (int k = 0; k < 4; ++k) {
      a0[k] += (f32x2){__builtin_bit_cast(float, d[k] << 16),
                       __builtin_bit_cast(float, d[k] & 0xffff0000u)};
    }
  }
#pragma unroll
  for (int k = 0; k < 4; ++k) a0[k] += a1[k];
  if (active) {
    int c = hi - lo; if (c < 1) c = 1;
    float inv = 1.0f / (float)c;
    short8 o;
#pragma unroll
    for (int k = 0; k < 4; ++k) {
      o[2 * k] = f2bf(a0[k].x * inv);
      o[2 * k + 1] = f2bf(a0[k].y * inv);
    }
    *reinterpret_cast<short8*>(ob + (size_t)row * 256 + l32 * 8) = o;
  }
}

// ---------------- bf16 MFMA GEMM: BM=128, BN=256, BK=32, 2-phase dbuf pipeline ----------------
// Swizzle f(row) = (row>>1)&3: bank-start = 16*(r&1) + 4*(cg^f(r)) -> uniform over
// {0,4,...,28}, 8 hits each = LDS minimum (fixes R15's 7.7M 4-way conflicts).
struct Srcs4 { const short* s[4]; };
struct GArgs {
  Srcs4 srcs; const short* Bt; const float* bias;
  int M; int K; short* outb; float* outf;
};

__device__ __forceinline__ void gemm_stage(const GArgs& a, short* sm, int m0,
                                           int k0, int sel, int w, int lane) {
  short* Abuf = sm + sel * 12288;
  short* Bbuf = sm + sel * 12288 + 4096;
  const short* Aq = a.srcs.s[k0 >> 8];
  const int kc = k0 & 255;
  const int M = a.M;
  {
    const int rbase = w * 16;
    const int row = rbase + (lane >> 2);
    const int cs = ((lane & 3) ^ ((row >> 1) & 3)) << 3;   // pre-swizzled source chunk
    int gr = m0 + row; gr = gr < M ? gr : M - 1;
    load_lds16(Aq + (size_t)gr * 256 + kc + cs, &Abuf[rbase * 32]);
  }
#pragma unroll
  for (int rr = 0; rr < 2; ++rr) {
    const int rbase = w * 32 + rr * 16;
    const int row = rbase + (lane >> 2);
    const int cs = ((lane & 3) ^ ((row >> 1) & 3)) << 3;
    load_lds16(a.Bt + (size_t)row * a.K + k0 + cs, &Bbuf[rbase * 32]);
  }
}

__device__ __forceinline__ void gemm_body(const GArgs& a, int bx) {
  __shared__ short sm[24576];
  const int tid = threadIdx.x;
  const int lane = tid & 63;
  const int w = tid >> 6;             // 0..7
  const int wr = w >> 2, wc = w & 3;  // 2 x 4 wave grid
  const int m0 = bx * 128;
  const int M = a.M, K = a.K;

  f32x4 acc[4][4];
#pragma unroll
  for (int i = 0; i < 4; ++i)
#pragma unroll
    for (int j = 0; j < 4; ++j) acc[i][j] = (f32x4){0.f, 0.f, 0.f, 0.f};

  const int nt = K >> 5;
  gemm_stage(a, sm, m0, 0, 0, w, lane);
  __syncthreads();
  int sel = 0;
  for (int t = 0; t < nt; ++t) {
    if (t + 1 < nt) gemm_stage(a, sm, m0, (t + 1) << 5, sel ^ 1, w, lane);
    {
      const short* Abuf = sm + sel * 12288;
      const short* Bbuf = sm + sel * 12288 + 4096;
      const int cg = lane >> 4;                      // k-chunk 0..3
      bf16x8 af[4], bfr[4];
#pragma unroll
      for (int mi = 0; mi < 4; ++mi) {
        const int r = wr * 64 + mi * 16 + (lane & 15);
        af[mi] = *reinterpret_cast<const bf16x8*>(&Abuf[r * 32 + ((cg ^ ((r >> 1) & 3)) << 3)]);
      }
#pragma unroll
      for (int nj = 0; nj < 4; ++nj) {
        const int r = wc * 64 + nj * 16 + (lane & 15);
        bfr[nj] = *reinterpret_cast<const bf16x8*>(&Bbuf[r * 32 + ((cg ^ ((r >> 1) & 3)) << 3)]);
      }
#pragma unroll
      for (int mi = 0; mi < 4; ++mi)
#pragma unroll
        for (int nj = 0; nj < 4; ++nj)
          acc[mi][nj] = __builtin_amdgcn_mfma_f32_16x16x32_bf16(af[mi], bfr[nj], acc[mi][nj], 0, 0, 0);
    }
    __syncthreads();   // drains prefetch loads (vmcnt) + protects buffer reuse
    sel ^= 1;
  }

  const int rb = (lane >> 4) << 2;
  const int cl = lane & 15;

  if (a.outb) {
#pragma unroll
    for (int halfp = 0; halfp < 2; ++halfp) {
      __syncthreads();
      if (wr == halfp) {
#pragma unroll
        for (int mi = 0; mi < 4; ++mi)
#pragma unroll
          for (int nj = 0; nj < 4; ++nj) {
            const int col = wc * 64 + nj * 16 + cl;
            const float bv = a.bias[col];
#pragma unroll
            for (int j = 0; j < 4; ++j) {
              const int rloc = mi * 16 + rb + j;
              float v = fmaxf(acc[mi][nj][j] + bv, 0.0f);
              sm[rloc * 264 + col] = f2bf(v);
            }
          }
      }
      __syncthreads();
#pragma unroll
      for (int q = 0; q < 4; ++q) {
        int c = q * 512 + tid;
        int rloc = c >> 5;
        int coff = (c & 31) * 8;
        int grow = m0 + halfp * 64 + rloc;
        if (grow < M) {
          short8 vv = *reinterpret_cast<const short8*>(&sm[rloc * 264 + coff]);
          *reinterpret_cast<short8*>(a.outb + (size_t)grow * 256 + coff) = vv;
        }
      }
    }
  }
  if (a.outf) {
    float* fsm = reinterpret_cast<float*>(sm);
#pragma unroll
    for (int p = 0; p < 4; ++p) {
      __syncthreads();
      if (wr == (p >> 1)) {
#pragma unroll
        for (int mm = 0; mm < 2; ++mm) {
          const int mi = (p & 1) * 2 + mm;
#pragma unroll
          for (int nj = 0; nj < 4; ++nj) {
            const int col = wc * 64 + nj * 16 + cl;
            const float bv = a.bias[col];
#pragma unroll
            for (int j = 0; j < 4; ++j) {
              const int rloc = mi * 16 + rb + j - (p & 1) * 32;
              float v = fmaxf(acc[mi][nj][j] + bv, 0.0f);
              fsm[rloc * 260 + col] = v;
            }
          }
        }
      }
      __syncthreads();
#pragma unroll
      for (int q = 0; q < 4; ++q) {
        int c = q * 512 + tid;
        int rloc = c >> 6;
        int coff = (c & 63) * 4;
        int grow = m0 + p * 32 + rloc;
        if (grow < M) {
          float4 vv = *reinterpret_cast<const float4*>(&fsm[rloc * 260 + coff]);
          *reinterpret_cast<float4*>(a.outf + (size_t)grow * 256 + coff) = vv;
        }
      }
    }
  }
}

__global__ __launch_bounds__(512) void gemm_bt(GArgs a) {
  gemm_body(a, blockIdx.x);
}

__global__ __launch_bounds__(512) void gemm_multi3(GArgs a0, GArgs a1, GArgs a2,
                                                   int nb0, int nb01) {
  int bx = blockIdx.x;
  if (bx < nb0) gemm_body(a0, bx);
  else if (bx < nb01) gemm_body(a1, bx - nb0);
  else gemm_body(a2, bx - nb01);
}

// ---------------- pooling (two-stage) + MLP ----------------
__device__ __forceinline__ int lower_bound(const int* a, int n, int v) {
  int lo = 0, hi = n;
  while (lo < hi) { int mid = (lo + hi) >> 1; if (a[mid] < v) lo = mid + 1; else hi = mid; }
  return lo;
}

__global__ void pool_partial(const float* __restrict__ c2, const int* __restrict__ batch,
                             float* __restrict__ pooled_sum) {
  int r0 = blockIdx.x * 64;
  int t = threadIdx.x;
  float acc = 0.f;
  int prevb = batch[r0];
  for (int i = 0; i < 64; ++i) {
    int r = r0 + i;
    int b = batch[r];
    if (b != prevb) {
      atomicAdd(&pooled_sum[prevb * 256 + t], acc);
      acc = 0.f; prevb = b;
    }
    acc += c2[(size_t)r * 256 + t];
  }
  atomicAdd(&pooled_sum[prevb * 256 + t], acc);
}

__global__ void mlp_kernel(const float* __restrict__ pooled_sum, const int* __restrict__ batch,
                           const float* __restrict__ train,
                           const float* __restrict__ fc1w, const float* __restrict__ fc1b,
                           const float* __restrict__ fc2w, const float* __restrict__ fc2b,
                           float* __restrict__ out) {
  int b = blockIdx.x, t = threadIdx.x;
  __shared__ float x[288];
  __shared__ float hsm[128];
  __shared__ float sinv;
  if (t == 0) {
    int lo = lower_bound(batch, NCH, b);
    int hi = lower_bound(batch, NCH, b + 1);
    int c = hi - lo; if (c < 1) c = 1;
    sinv = 1.0f / (float)c;
  }
  __syncthreads();
  float inv = sinv;
  x[t] = pooled_sum[b * 256 + t] * inv;
  x[128 + t] = pooled_sum[b * 256 + 128 + t] * inv;
  if (t < 32) x[256 + t] = train[b * 32 + t];
  __syncthreads();
  float s = fc1b[t];
  for (int i = 0; i < 288; ++i) s += x[i] * fc1w[i * 128 + t];
  hsm[t] = fmaxf(s, 0.f);
  __syncthreads();
  if (t < 16) {
    float o = fc2b[t];
    for (int i = 0; i < 128; ++i) o += hsm[i] * fc2w[i * 16 + t];
    out[b * 16 + t] = o;
  }
}

// ---------------- launch ----------------
extern "C" void kernel_launch(void* const* d_in, const int* in_sizes, int n_in,
                              void* d_out, int out_size, void* d_ws, size_t ws_size,
                              hipStream_t stream) {
  const float* x_hru = (const float*)d_in[0];
  const float* x_ch  = (const float*)d_in[1];
  const float* x_gw  = (const float*)d_in[2];
  const int* src_swgw = (const int*)d_in[3];
  const int* dst_swgw = (const int*)d_in[4];
  const int* src_hyd  = (const int*)d_in[5];
  const int* dst_hyd  = (const int*)d_in[6];
  const int* src_sw   = (const int*)d_in[7];
  const int* dst_sw   = (const int*)d_in[8];
  const int* src_gwsw = (const int*)d_in[9];
  const int* dst_gwsw = (const int*)d_in[10];
  const int* src_slf  = (const int*)d_in[11];
  const int* dst_slf  = (const int*)d_in[12];
  const int* batch    = (const int*)d_in[13];
  const float* train  = (const float*)d_in[14];
  const float* Wl     = (const float*)d_in[15];
  const float* Wr     = (const float*)d_in[16];
  const float* bs     = (const float*)d_in[17];
  const float* fc1w   = (const float*)d_in[18];
  const float* fc1b   = (const float*)d_in[19];
  const float* fc2w   = (const float*)d_in[20];
  const float* fc2b   = (const float*)d_in[21];
  float* out = (float*)d_out;

  char* ws = (char*)d_ws;
  size_t off = 0;
  auto alloc = [&](size_t bytes) -> void* {
    off = (off + 255) & ~(size_t)255;
    void* p = ws + off;
    off += bytes;
    return p;
  };

  short* xb0h = (short*)alloc((size_t)NHRU * 256 * 2);
  short* xb0c = (short*)alloc((size_t)NCH * 256 * 2);
  short* xb0g = (short*)alloc((size_t)NGW * 256 * 2);
  short* xb1h = (short*)alloc((size_t)NHRU * 256 * 2);
  short* xb1c = (short*)alloc((size_t)NCH * 256 * 2);
  short* xb1g = (short*)alloc((size_t)NGW * 256 * 2);
  short* agg_gw  = (short*)alloc((size_t)NGW * 256 * 2);
  short* agg_c0  = (short*)alloc((size_t)NCH * 256 * 2);
  short* agg_c1  = (short*)alloc((size_t)NCH * 256 * 2);
  short* agg_c2  = (short*)alloc((size_t)NCH * 256 * 2);
  short* agg_hru = (short*)alloc((size_t)NHRU * 256 * 2);
  float* c2f = (float*)alloc((size_t)NCH * 256 * 4);
  int* cnt  = (int*)alloc(NCNT * 4);
  int* rp   = (int*)alloc((NCNT + 1) * 4);
  int* rank = (int*)alloc((size_t)5 * E_EDGES * 4);
  int* bsum = (int*)alloc(NBLK_SCAN * 4);
  int* boff = (int*)alloc(NBLK_SCAN * 4);
  int* ssrc = (int*)alloc((size_t)5 * E_EDGES * 4);
  short* BtBuf = (short*)alloc(786432 * 2);
  float* biasBuf = (float*)alloc(1024 * 4);
  float* pooled_sum = (float*)alloc(64 * 256 * 4);

  hipMemsetAsync(cnt, 0, NCNT * 4, stream);
  hipMemsetAsync(pooled_sum, 0, 64 * 256 * 4, stream);

  P5 dsts; dsts.p[0] = dst_swgw; dsts.p[1] = dst_hyd; dsts.p[2] = dst_sw;
  dsts.p[3] = dst_gwsw; dsts.p[4] = dst_slf;
  P5 srcs; srcs.p[0] = src_swgw; srcs.p[1] = src_hyd; srcs.p[2] = src_sw;
  srcs.p[3] = src_gwsw; srcs.p[4] = src_slf;

  // fused front-end: count_rank | cvt | prep_w
  fused_pre<<<NB_CNT + NB_CVT + NB_PREP, 256, 0, stream>>>(
      x_hru, x_ch, x_gw, xb0h, xb0c, xb0g,
      Wl, Wr, bs, BtBuf, biasBuf, dsts, cnt, rank);

  scan_a<<<NBLK_SCAN, 256, 0, stream>>>(cnt, bsum);
  scan_b<<<1, 1024, 0, stream>>>(bsum, boff);
  scan_c<<<NBLK_SCAN, 256, 0, stream>>>(cnt, boff, rp);
  dim3 eg(NB_E, 5);
  scatter_kernel<<<eg, 256, 0, stream>>>(srcs, dsts, rp, rank, ssrc);

  // layer 1: all 5 relations, single dispatch
  {
    AggTab t0{};
    t0.src[0] = xb0h; t0.out[0] = agg_gw;
    t0.src[1] = xb0c; t0.out[1] = agg_c0;
    t0.src[2] = xb0h; t0.out[2] = agg_c1;
    t0.src[3] = xb0g; t0.out[3] = agg_c2;
    t0.src[4] = xb0h; t0.out[4] = agg_hru;
    agg_pair<<<35000, 256, 0, stream>>>(rp, ssrc, t0, 7500, 12500, 17500, 22500, 0, 1, 2, 3, 4);
  }

  // layer 1 GEMMs (merged, ch-first: ch | gw | hru)
  {
    GArgs g0{}, g1{}, g2{};
    g0.srcs.s[0] = agg_c0; g0.srcs.s[1] = agg_c1; g0.srcs.s[2] = agg_c2; g0.srcs.s[3] = xb0c;
    g0.Bt = BtBuf + 131072; g0.bias = biasBuf + 256; g0.M = NCH; g0.K = 1024;
    g0.outb = xb1c; g0.outf = nullptr;
    g1.srcs.s[0] = agg_gw; g1.srcs.s[1] = xb0g;
    g1.Bt = BtBuf + 0; g1.bias = biasBuf + 0; g1.M = NGW; g1.K = 512;
    g1.outb = xb1g; g1.outf = nullptr;
    g2.srcs.s[0] = agg_hru; g2.srcs.s[1] = xb0h;
    g2.Bt = BtBuf + 393216; g2.bias = biasBuf + 512; g2.M = NHRU; g2.K = 512;
    g2.outb = xb1h; g2.outf = nullptr;
    const int nb0 = (NCH + 127) / 128;
    const int nb1 = (NGW + 127) / 128;
    const int nb2 = (NHRU + 127) / 128;
    gemm_multi3<<<dim3(nb0 + nb1 + nb2), 512, 0, stream>>>(g0, g1, g2, nb0, nb0 + nb1);
  }

  // layer 2: channel-dst relations (hyd, sw, gwsw), single dispatch
  {
    AggTab t1{};
    t1.src[1] = xb1c; t1.out[1] = agg_c0;
    t1.src[2] = xb1h; t1.out[2] = agg_c1;
    t1.src[3] = xb1g; t1.out[3] = agg_c2;
    agg_pair<<<15000, 256, 0, stream>>>(rp, ssrc, t1, 5000, 10000, 15000, 15000, 1, 2, 3, 3, 3);
  }

  // layer 2 channel GEMM -> fp32 c2
  {
    GArgs g{};
    g.srcs.s[0] = agg_c0; g.srcs.s[1] = agg_c1; g.srcs.s[2] = agg_c2; g.srcs.s[3] = xb1c;
    g.Bt = BtBuf + 524288; g.bias = biasBuf + 768; g.M = NCH; g.K = 1024;
    g.outb = nullptr; g.outf = c2f;
    gemm_bt<<<dim3((NCH + 127) / 128), 512, 0, stream>>>(g);
  }

  pool_partial<<<625, 256, 0, stream>>>(c2f, batch, pooled_sum);
  mlp_kernel<<<64, 128, 0, stream>>>(pooled_sum, batch, train, fc1w, fc1b, fc2w, fc2b, out);

  (void)in_sizes; (void)n_in; (void)out_size; (void)ws_size;
}

// Round 17
// 460.494 us; speedup vs baseline: 1.0989x; 1.0501x over previous
//
#include <hip/hip_runtime.h>

#define E_EDGES 250000
#define NHRU 100000
#define NCH  40000
#define NGW  60000
#define NCNT 280000
#define NBLK_SCAN 1094

// fused_pre block ranges: cvt(+50 fused count edges each) | prep
#define NB_CVT  25000
#define NB_PREP 3076
#define NB_E    977

typedef __attribute__((ext_vector_type(4))) float f32x4;
typedef __attribute__((ext_vector_type(2))) float f32x2;
typedef __attribute__((ext_vector_type(8))) __bf16 bf16x8;
typedef __attribute__((ext_vector_type(8))) short short8;

__device__ __forceinline__ float bf2f(short h) {
  unsigned u = ((unsigned)(unsigned short)h) << 16;
  return __builtin_bit_cast(float, u);
}
__device__ __forceinline__ short f2bf(float f) {
  unsigned u = __builtin_bit_cast(unsigned, f);
  u = u + 0x7fffu + ((u >> 16) & 1u);
  return (short)(u >> 16);
}

__device__ __forceinline__ void load_lds16(const void* g, void* lds) {
  __builtin_amdgcn_global_load_lds(
      (const __attribute__((address_space(1))) unsigned*)g,
      (__attribute__((address_space(3))) unsigned*)lds, 16, 0, 0);
}

struct P5 { const int* p[5]; };

// ---------------- fused front-end: cvt3 (+intra-block count) | prep_w ----------------
// Each cvt block also owns 50 edges of the 1.25M count space (threads 0..49):
// the atomic RTT is issued early and hides under the block's streaming loads.
__global__ void fused_pre(const float* __restrict__ xh, const float* __restrict__ xc,
                          const float* __restrict__ xg, short* __restrict__ oh,
                          short* __restrict__ oc, short* __restrict__ og,
                          const float* __restrict__ Wl, const float* __restrict__ Wr,
                          const float* __restrict__ bs, short* __restrict__ Bt,
                          float* __restrict__ bias,
                          P5 dst, int* __restrict__ cnt, int* __restrict__ rank) {
  int b = blockIdx.x;
  if (b < NB_CVT) {
    const int COFF[5] = {0, 60000, 100000, 140000, 180000};
    // fused count+rank: 50 edges per block (issued first, waited at rank store)
    if (threadIdx.x < 50) {
      int g = b * 50 + threadIdx.x;
      int r = g / E_EDGES;
      int e = g - r * E_EDGES;
      int d = dst.p[r][e];
      int rk = atomicAdd(&cnt[COFF[r] + d], 1);
      rank[r * E_EDGES + e] = rk;
    }
    // ---- fp32 -> bf16 convert, 32B/thread, nt loads ----
    int i = b * 256 + threadIdx.x;   // unit = 8 floats
    const int n1 = NHRU * 32, n2 = n1 + NCH * 32;
    const float* in; short* out; int j;
    if (i < n1) { in = xh; out = oh; j = i; }
    else if (i < n2) { in = xc; out = oc; j = i - n1; }
    else { in = xg; out = og; j = i - n2; }
    const f32x4* p = reinterpret_cast<const f32x4*>(in) + (size_t)j * 2;
    f32x4 v0 = __builtin_nontemporal_load(p);
    f32x4 v1 = __builtin_nontemporal_load(p + 1);
    short8 o;
#pragma unroll
    for (int k = 0; k < 4; ++k) { o[k] = f2bf(v0[k]); o[4 + k] = f2bf(v1[k]); }
    reinterpret_cast<short8*>(out)[j] = o;
  } else {
    // ---- weight prep: transpose + bf16 + fold /3 ----
    int i = (b - NB_CVT) * 256 + threadIdx.x;
    const float inv3 = 1.0f / 3.0f;
    if (i < 131072) {                       // gw: l=0,r=0
      int n = i >> 9, k = i & 511;
      float v = (k < 256) ? Wl[(0 * 256 + k) * 256 + n]
                          : Wr[(0 * 256 + (k - 256)) * 256 + n];
      Bt[i] = f2bf(v);
    } else if (i < 393216) {                // ch l=0
      int j = i - 131072;
      int n = j >> 10, k = j & 1023;
      float v;
      if (k < 768) {
        int r = 1 + (k >> 8), kk = k & 255;
        v = Wl[((0 * 5 + r) * 256 + kk) * 256 + n] * inv3;
      } else {
        int kk = k - 768;
        v = (Wr[((0 * 5 + 1) * 256 + kk) * 256 + n] +
             Wr[((0 * 5 + 2) * 256 + kk) * 256 + n] +
             Wr[((0 * 5 + 3) * 256 + kk) * 256 + n]) * inv3;
      }
      Bt[i] = f2bf(v);
    } else if (i < 524288) {                // hru: l=0,r=4
      int j = i - 393216;
      int n = j >> 9, k = j & 511;
      float v = (k < 256) ? Wl[((0 * 5 + 4) * 256 + k) * 256 + n]
                          : Wr[((0 * 5 + 4) * 256 + (k - 256)) * 256 + n];
      Bt[i] = f2bf(v);
    } else if (i < 786432) {                // ch l=1
      int j = i - 524288;
      int n = j >> 10, k = j & 1023;
      float v;
      if (k < 768) {
        int r = 1 + (k >> 8), kk = k & 255;
        v = Wl[((5 + r) * 256 + kk) * 256 + n] * inv3;
      } else {
        int kk = k - 768;
        v = (Wr[((5 + 1) * 256 + kk) * 256 + n] +
             Wr[((5 + 2) * 256 + kk) * 256 + n] +
             Wr[((5 + 3) * 256 + kk) * 256 + n]) * inv3;
      }
      Bt[i] = f2bf(v);
    } else if (i < 787456) {                // biases
      int j = i - 786432;
      int g = j >> 8, n = j & 255;
      float v;
      if (g == 0)      v = bs[n];
      else if (g == 1) v = (bs[256 + n] + bs[512 + n] + bs[768 + n]) * inv3;
      else if (g == 2) v = bs[1024 + n];
      else             v = (bs[1280 + 256 + n] + bs[1280 + 512 + n] + bs[1280 + 768 + n]) * inv3;
      bias[j] = v;
    }
  }
}

// ---------------- global scan (3 kernels) ----------------
__global__ void scan_a(const int* __restrict__ cnt, int* __restrict__ bsum) {
  int i = blockIdx.x * 256 + threadIdx.x;
  int v = (i < NCNT) ? cnt[i] : 0;
  int lane = threadIdx.x & 63, wv = threadIdx.x >> 6;
  for (int d = 1; d < 64; d <<= 1) v += __shfl_down(v, d);
  __shared__ int ws[4];
  if (lane == 0) ws[wv] = v;
  __syncthreads();
  if (threadIdx.x == 0) bsum[blockIdx.x] = ws[0] + ws[1] + ws[2] + ws[3];
}

__global__ void scan_b(const int* __restrict__ bsum, int* __restrict__ boff) {
  int t = threadIdx.x;
  int e0 = 2 * t, e1 = 2 * t + 1;
  int v0 = (e0 < NBLK_SCAN) ? bsum[e0] : 0;
  int v1 = (e1 < NBLK_SCAN) ? bsum[e1] : 0;
  __shared__ int lds[1024];
  lds[t] = v0 + v1;
  __syncthreads();
  for (int o = 1; o < 1024; o <<= 1) {
    int add = (t >= o) ? lds[t - o] : 0;
    __syncthreads();
    lds[t] += add;
    __syncthreads();
  }
  int ex = (t == 0) ? 0 : lds[t - 1];
  if (e0 < NBLK_SCAN) boff[e0] = ex;
  if (e1 < NBLK_SCAN) boff[e1] = ex + v0;
}

__global__ void scan_c(const int* __restrict__ cnt, const int* __restrict__ boff,
                       int* __restrict__ S) {
  int i = blockIdx.x * 256 + threadIdx.x;
  int v = (i < NCNT) ? cnt[i] : 0;
  int lane = threadIdx.x & 63, wv = threadIdx.x >> 6;
  int inc = v;
  for (int d = 1; d < 64; d <<= 1) {
    int y = __shfl_up(inc, d);
    if (lane >= d) inc += y;
  }
  __shared__ int ws[4];
  if (lane == 63) ws[wv] = inc;
  __syncthreads();
  int wex = 0;
  for (int k = 0; k < 4; ++k) wex += (k < wv) ? ws[k] : 0;
  int ex = boff[blockIdx.x] + wex + inc - v;
  if (i < NCNT) S[i] = ex;
  if (blockIdx.x == 0 && threadIdx.x == 0) S[NCNT] = 5 * E_EDGES;
}

// pass 2: scatter without atomics
__global__ void scatter_kernel(P5 src, P5 dst, const int* __restrict__ rp,
                               const int* __restrict__ rank, int* __restrict__ ssrc) {
  const int COFF[5] = {0, 60000, 100000, 140000, 180000};
  int r = blockIdx.y;
  int e = blockIdx.x * blockDim.x + threadIdx.x;
  if (e < E_EDGES) {
    int d = dst.p[r][e];
    int idx = rp[COFF[r] + d] + rank[r * E_EDGES + e];
    ssrc[idx] = src.p[r][e];
  }
}

// ---------------- paired mean aggregation: 2 items/wave, 2 gather chains per half ----------------
struct AggTab { const short* src[5]; short* out[5]; };

__global__ void agg_pair(const int* __restrict__ rp, const int* __restrict__ ssrc,
                         AggTab tab, int be0, int be1, int be2, int be3,
                         int r0, int r1, int r2, int r3, int r4) {
  int b = blockIdx.x;
  int r, b0;
  if (b < be0)      { r = r0; b0 = 0; }
  else if (b < be1) { r = r1; b0 = be0; }
  else if (b < be2) { r = r2; b0 = be1; }
  else if (b < be3) { r = r3; b0 = be2; }
  else              { r = r4; b0 = be3; }
  int coff = r == 0 ? 0 : r == 1 ? 60000 : r == 2 ? 100000 : r == 3 ? 140000 : 180000;
  int nrel = r == 0 ? 60000 : r == 4 ? 100000 : 40000;
  const short* xs = r == 0 ? tab.src[0] : r == 1 ? tab.src[1] : r == 2 ? tab.src[2]
                   : r == 3 ? tab.src[3] : tab.src[4];
  short* ob = r == 0 ? tab.out[0] : r == 1 ? tab.out[1] : r == 2 ? tab.out[2]
             : r == 3 ? tab.out[3] : tab.out[4];

  int wid = threadIdx.x >> 6;
  int lane = threadIdx.x & 63;
  int half = lane >> 5, l32 = lane & 31;
  int row = (b - b0) * 8 + wid * 2 + half;
  bool active = row < nrel;
  int item = coff + row;
  int lo = 0, hi = 0;
  if (active) { lo = rp[item]; hi = rp[item + 1]; }

  f32x2 a0[4], a1[4];
#pragma unroll
  for (int k = 0; k < 4; ++k) { a0[k] = (f32x2){0.f, 0.f}; a1[k] = (f32x2){0.f, 0.f}; }
  int e = lo;
  for (; e + 1 < hi; e += 2) {
    int s0 = ssrc[e];
    int s1 = ssrc[e + 1];
    uint4 u0 = *reinterpret_cast<const uint4*>(xs + (size_t)s0 * 256 + l32 * 8);
    uint4 u1 = *reinterpret_cast<const uint4*>(xs + (size_t)s1 * 256 + l32 * 8);
    unsigned d0[4] = {u0.x, u0.y, u0.z, u0.w};
    unsigned d1[4] = {u1.x, u1.y, u1.z, u1.w};
#pragma unroll
    for (int k = 0; k < 4; ++k) {
      a0[k] += (f32x2){__builtin_bit_cast(float, d0[k] << 16),
                       __builtin_bit_cast(float, d0[k] & 0xffff0000u)};
      a1[k] += (f32x2){__builtin_bit_cast(float, d1[k] << 16),
                       __builtin_bit_cast(float, d1[k] & 0xffff0000u)};
    }
  }
  if (e < hi) {
    int s = ssrc[e];
    uint4 u = *reinterpret_cast<const uint4*>(xs + (size_t)s * 256 + l32 * 8);
    unsigned d[4] = {u.x, u.y, u.z, u.w};
#pragma unroll
    for (int k = 0; k < 4; ++k) {
      a0[k] += (f32x2){__builtin_bit_cast(float, d[k] << 16),
                       __builtin_bit_cast(float, d[k] & 0xffff0000u)};
    }
  }
#pragma unroll
  for (int k = 0; k < 4; ++k) a0[k] += a1[k];
  if (active) {
    int c = hi - lo; if (c < 1) c = 1;
    float inv = 1.0f / (float)c;
    short8 o;
#pragma unroll
    for (int k = 0; k < 4; ++k) {
      o[2 * k] = f2bf(a0[k].x * inv);
      o[2 * k + 1] = f2bf(a0[k].y * inv);
    }
    *reinterpret_cast<short8*>(ob + (size_t)row * 256 + l32 * 8) = o;
  }
}

// ---------------- bf16 MFMA GEMM: BM=128, BN=256, BK=32, 2-phase dbuf pipeline ----------------
struct Srcs4 { const short* s[4]; };
struct GArgs {
  Srcs4 srcs; const short* Bt; const float* bias;
  int M; int K; short* outb; float* outf;
};

__device__ __forceinline__ void gemm_stage(const GArgs& a, short* sm, int m0,
                                           int k0, int sel, int w, int lane) {
  short* Abuf = sm + sel * 12288;
  short* Bbuf = sm + sel * 12288 + 4096;
  const short* Aq = a.srcs.s[k0 >> 8];
  const int kc = k0 & 255;
  const int M = a.M;
  {
    const int rbase = w * 16;
    const int row = rbase + (lane >> 2);
    const int cs = ((lane & 3) ^ ((row >> 1) & 3)) << 3;   // pre-swizzled source chunk
    int gr = m0 + row; gr = gr < M ? gr : M - 1;
    load_lds16(Aq + (size_t)gr * 256 + kc + cs, &Abuf[rbase * 32]);
  }
#pragma unroll
  for (int rr = 0; rr < 2; ++rr) {
    const int rbase = w * 32 + rr * 16;
    const int row = rbase + (lane >> 2);
    const int cs = ((lane & 3) ^ ((row >> 1) & 3)) << 3;
    load_lds16(a.Bt + (size_t)row * a.K + k0 + cs, &Bbuf[rbase * 32]);
  }
}

__device__ __forceinline__ void gemm_body(const GArgs& a, int bx) {
  __shared__ short sm[24576];
  const int tid = threadIdx.x;
  const int lane = tid & 63;
  const int w = tid >> 6;             // 0..7
  const int wr = w >> 2, wc = w & 3;  // 2 x 4 wave grid
  const int m0 = bx * 128;
  const int M = a.M, K = a.K;

  f32x4 acc[4][4];
#pragma unroll
  for (int i = 0; i < 4; ++i)
#pragma unroll
    for (int j = 0; j < 4; ++j) acc[i][j] = (f32x4){0.f, 0.f, 0.f, 0.f};

  const int nt = K >> 5;
  gemm_stage(a, sm, m0, 0, 0, w, lane);
  __syncthreads();
  int sel = 0;
  for (int t = 0; t < nt; ++t) {
    if (t + 1 < nt) gemm_stage(a, sm, m0, (t + 1) << 5, sel ^ 1, w, lane);
    {
      const short* Abuf = sm + sel * 12288;
      const short* Bbuf = sm + sel * 12288 + 4096;
      const int cg = lane >> 4;                      // k-chunk 0..3
      bf16x8 af[4], bfr[4];
#pragma unroll
      for (int mi = 0; mi < 4; ++mi) {
        const int r = wr * 64 + mi * 16 + (lane & 15);
        af[mi] = *reinterpret_cast<const bf16x8*>(&Abuf[r * 32 + ((cg ^ ((r >> 1) & 3)) << 3)]);
      }
#pragma unroll
      for (int nj = 0; nj < 4; ++nj) {
        const int r = wc * 64 + nj * 16 + (lane & 15);
        bfr[nj] = *reinterpret_cast<const bf16x8*>(&Bbuf[r * 32 + ((cg ^ ((r >> 1) & 3)) << 3)]);
      }
#pragma unroll
      for (int mi = 0; mi < 4; ++mi)
#pragma unroll
        for (int nj = 0; nj < 4; ++nj)
          acc[mi][nj] = __builtin_amdgcn_mfma_f32_16x16x32_bf16(af[mi], bfr[nj], acc[mi][nj], 0, 0, 0);
    }
    __syncthreads();   // drains prefetch loads (vmcnt) + protects buffer reuse
    sel ^= 1;
  }

  const int rb = (lane >> 4) << 2;
  const int cl = lane & 15;

  if (a.outb) {
#pragma unroll
    for (int halfp = 0; halfp < 2; ++halfp) {
      __syncthreads();
      if (wr == halfp) {
#pragma unroll
        for (int mi = 0; mi < 4; ++mi)
#pragma unroll
          for (int nj = 0; nj < 4; ++nj) {
            const int col = wc * 64 + nj * 16 + cl;
            const float bv = a.bias[col];
#pragma unroll
            for (int j = 0; j < 4; ++j) {
              const int rloc = mi * 16 + rb + j;
              float v = fmaxf(acc[mi][nj][j] + bv, 0.0f);
              sm[rloc * 264 + col] = f2bf(v);
            }
          }
      }
      __syncthreads();
#pragma unroll
      for (int q = 0; q < 4; ++q) {
        int c = q * 512 + tid;
        int rloc = c >> 5;
        int coff = (c & 31) * 8;
        int grow = m0 + halfp * 64 + rloc;
        if (grow < M) {
          short8 vv = *reinterpret_cast<const short8*>(&sm[rloc * 264 + coff]);
          *reinterpret_cast<short8*>(a.outb + (size_t)grow * 256 + coff) = vv;
        }
      }
    }
  }
  if (a.outf) {
    float* fsm = reinterpret_cast<float*>(sm);
#pragma unroll
    for (int p = 0; p < 4; ++p) {
      __syncthreads();
      if (wr == (p >> 1)) {
#pragma unroll
        for (int mm = 0; mm < 2; ++mm) {
          const int mi = (p & 1) * 2 + mm;
#pragma unroll
          for (int nj = 0; nj < 4; ++nj) {
            const int col = wc * 64 + nj * 16 + cl;
            const float bv = a.bias[col];
#pragma unroll
            for (int j = 0; j < 4; ++j) {
              const int rloc = mi * 16 + rb + j - (p & 1) * 32;
              float v = fmaxf(acc[mi][nj][j] + bv, 0.0f);
              fsm[rloc * 260 + col] = v;
            }
          }
        }
      }
      __syncthreads();
#pragma unroll
      for (int q = 0; q < 4; ++q) {
        int c = q * 512 + tid;
        int rloc = c >> 6;
        int coff = (c & 63) * 4;
        int grow = m0 + p * 32 + rloc;
        if (grow < M) {
          float4 vv = *reinterpret_cast<const float4*>(&fsm[rloc * 260 + coff]);
          *reinterpret_cast<float4*>(a.outf + (size_t)grow * 256 + coff) = vv;
        }
      }
    }
  }
}

__global__ __launch_bounds__(512) void gemm_bt(GArgs a) {
  gemm_body(a, blockIdx.x);
}

__global__ __launch_bounds__(512) void gemm_multi3(GArgs a0, GArgs a1, GArgs a2,
                                                   int nb0, int nb01) {
  int bx = blockIdx.x;
  if (bx < nb0) gemm_body(a0, bx);
  else if (bx < nb01) gemm_body(a1, bx - nb0);
  else gemm_body(a2, bx - nb01);
}

// ---------------- pooling (two-stage) + MLP ----------------
__device__ __forceinline__ int lower_bound(const int* a, int n, int v) {
  int lo = 0, hi = n;
  while (lo < hi) { int mid = (lo + hi) >> 1; if (a[mid] < v) lo = mid + 1; else hi = mid; }
  return lo;
}

__global__ void pool_partial(const float* __restrict__ c2, const int* __restrict__ batch,
                             float* __restrict__ pooled_sum) {
  int r0 = blockIdx.x * 64;
  int t = threadIdx.x;
  float acc = 0.f;
  int prevb = batch[r0];
  for (int i = 0; i < 64; ++i) {
    int r = r0 + i;
    int b = batch[r];
    if (b != prevb) {
      atomicAdd(&pooled_sum[prevb * 256 + t], acc);
      acc = 0.f; prevb = b;
    }
    acc += c2[(size_t)r * 256 + t];
  }
  atomicAdd(&pooled_sum[prevb * 256 + t], acc);
}

__global__ void mlp_kernel(const float* __restrict__ pooled_sum, const int* __restrict__ batch,
                           const float* __restrict__ train,
                           const float* __restrict__ fc1w, const float* __restrict__ fc1b,
                           const float* __restrict__ fc2w, const float* __restrict__ fc2b,
                           float* __restrict__ out) {
  int b = blockIdx.x, t = threadIdx.x;
  __shared__ float x[288];
  __shared__ float hsm[128];
  __shared__ float sinv;
  if (t == 0) {
    int lo = lower_bound(batch, NCH, b);
    int hi = lower_bound(batch, NCH, b + 1);
    int c = hi - lo; if (c < 1) c = 1;
    sinv = 1.0f / (float)c;
  }
  __syncthreads();
  float inv = sinv;
  x[t] = pooled_sum[b * 256 + t] * inv;
  x[128 + t] = pooled_sum[b * 256 + 128 + t] * inv;
  if (t < 32) x[256 + t] = train[b * 32 + t];
  __syncthreads();
  float s = fc1b[t];
  for (int i = 0; i < 288; ++i) s += x[i] * fc1w[i * 128 + t];
  hsm[t] = fmaxf(s, 0.f);
  __syncthreads();
  if (t < 16) {
    float o = fc2b[t];
    for (int i = 0; i < 128; ++i) o += hsm[i] * fc2w[i * 16 + t];
    out[b * 16 + t] = o;
  }
}

// ---------------- launch ----------------
extern "C" void kernel_launch(void* const* d_in, const int* in_sizes, int n_in,
                              void* d_out, int out_size, void* d_ws, size_t ws_size,
                              hipStream_t stream) {
  const float* x_hru = (const float*)d_in[0];
  const float* x_ch  = (const float*)d_in[1];
  const float* x_gw  = (const float*)d_in[2];
  const int* src_swgw = (const int*)d_in[3];
  const int* dst_swgw = (const int*)d_in[4];
  const int* src_hyd  = (const int*)d_in[5];
  const int* dst_hyd  = (const int*)d_in[6];
  const int* src_sw   = (const int*)d_in[7];
  const int* dst_sw   = (const int*)d_in[8];
  const int* src_gwsw = (const int*)d_in[9];
  const int* dst_gwsw = (const int*)d_in[10];
  const int* src_slf  = (const int*)d_in[11];
  const int* dst_slf  = (const int*)d_in[12];
  const int* batch    = (const int*)d_in[13];
  const float* train  = (const float*)d_in[14];
  const float* Wl     = (const float*)d_in[15];
  const float* Wr     = (const float*)d_in[16];
  const float* bs     = (const float*)d_in[17];
  const float* fc1w   = (const float*)d_in[18];
  const float* fc1b   = (const float*)d_in[19];
  const float* fc2w   = (const float*)d_in[20];
  const float* fc2b   = (const float*)d_in[21];
  float* out = (float*)d_out;

  char* ws = (char*)d_ws;
  size_t off = 0;
  auto alloc = [&](size_t bytes) -> void* {
    off = (off + 255) & ~(size_t)255;
    void* p = ws + off;
    off += bytes;
    return p;
  };

  short* xb0h = (short*)alloc((size_t)NHRU * 256 * 2);
  short* xb0c = (short*)alloc((size_t)NCH * 256 * 2);
  short* xb0g = (short*)alloc((size_t)NGW * 256 * 2);
  short* xb1h = (short*)alloc((size_t)NHRU * 256 * 2);
  short* xb1c = (short*)alloc((size_t)NCH * 256 * 2);
  short* xb1g = (short*)alloc((size_t)NGW * 256 * 2);
  short* agg_gw  = (short*)alloc((size_t)NGW * 256 * 2);
  short* agg_c0  = (short*)alloc((size_t)NCH * 256 * 2);
  short* agg_c1  = (short*)alloc((size_t)NCH * 256 * 2);
  short* agg_c2  = (short*)alloc((size_t)NCH * 256 * 2);
  short* agg_hru = (short*)alloc((size_t)NHRU * 256 * 2);
  float* c2f = (float*)alloc((size_t)NCH * 256 * 4);
  int* cnt  = (int*)alloc(NCNT * 4);
  int* rp   = (int*)alloc((NCNT + 1) * 4);
  int* rank = (int*)alloc((size_t)5 * E_EDGES * 4);
  int* bsum = (int*)alloc(NBLK_SCAN * 4);
  int* boff = (int*)alloc(NBLK_SCAN * 4);
  int* ssrc = (int*)alloc((size_t)5 * E_EDGES * 4);
  short* BtBuf = (short*)alloc(786432 * 2);
  float* biasBuf = (float*)alloc(1024 * 4);
  float* pooled_sum = (float*)alloc(64 * 256 * 4);

  hipMemsetAsync(cnt, 0, NCNT * 4, stream);
  hipMemsetAsync(pooled_sum, 0, 64 * 256 * 4, stream);

  P5 dsts; dsts.p[0] = dst_swgw; dsts.p[1] = dst_hyd; dsts.p[2] = dst_sw;
  dsts.p[3] = dst_gwsw; dsts.p[4] = dst_slf;
  P5 srcs; srcs.p[0] = src_swgw; srcs.p[1] = src_hyd; srcs.p[2] = src_sw;
  srcs.p[3] = src_gwsw; srcs.p[4] = src_slf;

  // fused front-end: cvt (+intra-block count) | prep_w
  fused_pre<<<NB_CVT + NB_PREP, 256, 0, stream>>>(
      x_hru, x_ch, x_gw, xb0h, xb0c, xb0g,
      Wl, Wr, bs, BtBuf, biasBuf, dsts, cnt, rank);

  scan_a<<<NBLK_SCAN, 256, 0, stream>>>(cnt, bsum);
  scan_b<<<1, 1024, 0, stream>>>(bsum, boff);
  scan_c<<<NBLK_SCAN, 256, 0, stream>>>(cnt, boff, rp);
  dim3 eg(NB_E, 5);
  scatter_kernel<<<eg, 256, 0, stream>>>(srcs, dsts, rp, rank, ssrc);

  // layer 1: all 5 relations, single dispatch
  {
    AggTab t0{};
    t0.src[0] = xb0h; t0.out[0] = agg_gw;
    t0.src[1] = xb0c; t0.out[1] = agg_c0;
    t0.src[2] = xb0h; t0.out[2] = agg_c1;
    t0.src[3] = xb0g; t0.out[3] = agg_c2;
    t0.src[4] = xb0h; t0.out[4] = agg_hru;
    agg_pair<<<35000, 256, 0, stream>>>(rp, ssrc, t0, 7500, 12500, 17500, 22500, 0, 1, 2, 3, 4);
  }

  // layer 1 GEMMs (merged, ch-first: ch | gw | hru)
  {
    GArgs g0{}, g1{}, g2{};
    g0.srcs.s[0] = agg_c0; g0.srcs.s[1] = agg_c1; g0.srcs.s[2] = agg_c2; g0.srcs.s[3] = xb0c;
    g0.Bt = BtBuf + 131072; g0.bias = biasBuf + 256; g0.M = NCH; g0.K = 1024;
    g0.outb = xb1c; g0.outf = nullptr;
    g1.srcs.s[0] = agg_gw; g1.srcs.s[1] = xb0g;
    g1.Bt = BtBuf + 0; g1.bias = biasBuf + 0; g1.M = NGW; g1.K = 512;
    g1.outb = xb1g; g1.outf = nullptr;
    g2.srcs.s[0] = agg_hru; g2.srcs.s[1] = xb0h;
    g2.Bt = BtBuf + 393216; g2.bias = biasBuf + 512; g2.M = NHRU; g2.K = 512;
    g2.outb = xb1h; g2.outf = nullptr;
    const int nb0 = (NCH + 127) / 128;
    const int nb1 = (NGW + 127) / 128;
    const int nb2 = (NHRU + 127) / 128;
    gemm_multi3<<<dim3(nb0 + nb1 + nb2), 512, 0, stream>>>(g0, g1, g2, nb0, nb0 + nb1);
  }

  // layer 2: channel-dst relations (hyd, sw, gwsw), single dispatch
  {
    AggTab t1{};
    t1.src[1] = xb1c; t1.out[1] = agg_c0;
    t1.src[2] = xb1h; t1.out[2] = agg_c1;
    t1.src[3] = xb1g; t1.out[3] = agg_c2;
    agg_pair<<<15000, 256, 0, stream>>>(rp, ssrc, t1, 5000, 10000, 15000, 15000, 1, 2, 3, 3, 3);
  }

  // layer 2 channel GEMM -> fp32 c2
  {
    GArgs g{};
    g.srcs.s[0] = agg_c0; g.srcs.s[1] = agg_c1; g.srcs.s[2] = agg_c2; g.srcs.s[3] = xb1c;
    g.Bt = BtBuf + 524288; g.bias = biasBuf + 768; g.M = NCH; g.K = 1024;
    g.outb = nullptr; g.outf = c2f;
    gemm_bt<<<dim3((NCH + 127) / 128), 512, 0, stream>>>(g);
  }

  pool_partial<<<625, 256, 0, stream>>>(c2f, batch, pooled_sum);
  mlp_kernel<<<64, 128, 0, stream>>>(pooled_sum, batch, train, fc1w, fc1b, fc2w, fc2b, out);

  (void)in_sizes; (void)n_in; (void)out_size; (void)ws_size;
}

// Round 18
// 450.506 us; speedup vs baseline: 1.1233x; 1.0222x over previous
//
#include <hip/hip_runtime.h>

#define E_EDGES 250000
#define NHRU 100000
#define NCH  40000
#define NGW  60000
#define NCNT 280000
#define NBLK_SCAN 1094

// fused_pre block ranges: cvt(+50 fused count edges each) | prep
#define NB_CVT  25000
#define NB_PREP 3076
#define NB_E    977

typedef __attribute__((ext_vector_type(4))) float f32x4;
typedef __attribute__((ext_vector_type(2))) float f32x2;
typedef __attribute__((ext_vector_type(8))) __bf16 bf16x8;
typedef __attribute__((ext_vector_type(8))) short short8;

__device__ __forceinline__ float bf2f(short h) {
  unsigned u = ((unsigned)(unsigned short)h) << 16;
  return __builtin_bit_cast(float, u);
}
__device__ __forceinline__ short f2bf(float f) {
  unsigned u = __builtin_bit_cast(unsigned, f);
  u = u + 0x7fffu + ((u >> 16) & 1u);
  return (short)(u >> 16);
}

__device__ __forceinline__ void load_lds16(const void* g, void* lds) {
  __builtin_amdgcn_global_load_lds(
      (const __attribute__((address_space(1))) unsigned*)g,
      (__attribute__((address_space(3))) unsigned*)lds, 16, 0, 0);
}

struct P5 { const int* p[5]; };

// ---------------- fused front-end: cvt3 (+intra-block count) | prep_w ----------------
__global__ void fused_pre(const float* __restrict__ xh, const float* __restrict__ xc,
                          const float* __restrict__ xg, short* __restrict__ oh,
                          short* __restrict__ oc, short* __restrict__ og,
                          const float* __restrict__ Wl, const float* __restrict__ Wr,
                          const float* __restrict__ bs, short* __restrict__ Bt,
                          float* __restrict__ bias,
                          P5 dst, int* __restrict__ cnt, int* __restrict__ rank) {
  int b = blockIdx.x;
  if (b < NB_CVT) {
    const int COFF[5] = {0, 60000, 100000, 140000, 180000};
    // fused count+rank: 50 edges per block (atomic RTT hides under the stream)
    if (threadIdx.x < 50) {
      int g = b * 50 + threadIdx.x;
      int r = g / E_EDGES;
      int e = g - r * E_EDGES;
      int d = dst.p[r][e];
      int rk = atomicAdd(&cnt[COFF[r] + d], 1);
      rank[r * E_EDGES + e] = rk;
    }
    // ---- fp32 -> bf16 convert, 32B/thread, nt loads ----
    int i = b * 256 + threadIdx.x;   // unit = 8 floats
    const int n1 = NHRU * 32, n2 = n1 + NCH * 32;
    const float* in; short* out; int j;
    if (i < n1) { in = xh; out = oh; j = i; }
    else if (i < n2) { in = xc; out = oc; j = i - n1; }
    else { in = xg; out = og; j = i - n2; }
    const f32x4* p = reinterpret_cast<const f32x4*>(in) + (size_t)j * 2;
    f32x4 v0 = __builtin_nontemporal_load(p);
    f32x4 v1 = __builtin_nontemporal_load(p + 1);
    short8 o;
#pragma unroll
    for (int k = 0; k < 4; ++k) { o[k] = f2bf(v0[k]); o[4 + k] = f2bf(v1[k]); }
    reinterpret_cast<short8*>(out)[j] = o;
  } else {
    // ---- weight prep: transpose + bf16 + fold /3 ----
    int i = (b - NB_CVT) * 256 + threadIdx.x;
    const float inv3 = 1.0f / 3.0f;
    if (i < 131072) {                       // gw: l=0,r=0
      int n = i >> 9, k = i & 511;
      float v = (k < 256) ? Wl[(0 * 256 + k) * 256 + n]
                          : Wr[(0 * 256 + (k - 256)) * 256 + n];
      Bt[i] = f2bf(v);
    } else if (i < 393216) {                // ch l=0
      int j = i - 131072;
      int n = j >> 10, k = j & 1023;
      float v;
      if (k < 768) {
        int r = 1 + (k >> 8), kk = k & 255;
        v = Wl[((0 * 5 + r) * 256 + kk) * 256 + n] * inv3;
      } else {
        int kk = k - 768;
        v = (Wr[((0 * 5 + 1) * 256 + kk) * 256 + n] +
             Wr[((0 * 5 + 2) * 256 + kk) * 256 + n] +
             Wr[((0 * 5 + 3) * 256 + kk) * 256 + n]) * inv3;
      }
      Bt[i] = f2bf(v);
    } else if (i < 524288) {                // hru: l=0,r=4
      int j = i - 393216;
      int n = j >> 9, k = j & 511;
      float v = (k < 256) ? Wl[((0 * 5 + 4) * 256 + k) * 256 + n]
                          : Wr[((0 * 5 + 4) * 256 + (k - 256)) * 256 + n];
      Bt[i] = f2bf(v);
    } else if (i < 786432) {                // ch l=1
      int j = i - 524288;
      int n = j >> 10, k = j & 1023;
      float v;
      if (k < 768) {
        int r = 1 + (k >> 8), kk = k & 255;
        v = Wl[((5 + r) * 256 + kk) * 256 + n] * inv3;
      } else {
        int kk = k - 768;
        v = (Wr[((5 + 1) * 256 + kk) * 256 + n] +
             Wr[((5 + 2) * 256 + kk) * 256 + n] +
             Wr[((5 + 3) * 256 + kk) * 256 + n]) * inv3;
      }
      Bt[i] = f2bf(v);
    } else if (i < 787456) {                // biases
      int j = i - 786432;
      int g = j >> 8, n = j & 255;
      float v;
      if (g == 0)      v = bs[n];
      else if (g == 1) v = (bs[256 + n] + bs[512 + n] + bs[768 + n]) * inv3;
      else if (g == 2) v = bs[1024 + n];
      else             v = (bs[1280 + 256 + n] + bs[1280 + 512 + n] + bs[1280 + 768 + n]) * inv3;
      bias[j] = v;
    }
  }
}

// ---------------- global scan (3 kernels) ----------------
__global__ void scan_a(const int* __restrict__ cnt, int* __restrict__ bsum) {
  int i = blockIdx.x * 256 + threadIdx.x;
  int v = (i < NCNT) ? cnt[i] : 0;
  int lane = threadIdx.x & 63, wv = threadIdx.x >> 6;
  for (int d = 1; d < 64; d <<= 1) v += __shfl_down(v, d);
  __shared__ int ws[4];
  if (lane == 0) ws[wv] = v;
  __syncthreads();
  if (threadIdx.x == 0) bsum[blockIdx.x] = ws[0] + ws[1] + ws[2] + ws[3];
}

__global__ void scan_b(const int* __restrict__ bsum, int* __restrict__ boff) {
  int t = threadIdx.x;
  int e0 = 2 * t, e1 = 2 * t + 1;
  int v0 = (e0 < NBLK_SCAN) ? bsum[e0] : 0;
  int v1 = (e1 < NBLK_SCAN) ? bsum[e1] : 0;
  __shared__ int lds[1024];
  lds[t] = v0 + v1;
  __syncthreads();
  for (int o = 1; o < 1024; o <<= 1) {
    int add = (t >= o) ? lds[t - o] : 0;
    __syncthreads();
    lds[t] += add;
    __syncthreads();
  }
  int ex = (t == 0) ? 0 : lds[t - 1];
  if (e0 < NBLK_SCAN) boff[e0] = ex;
  if (e1 < NBLK_SCAN) boff[e1] = ex + v0;
}

__global__ void scan_c(const int* __restrict__ cnt, const int* __restrict__ boff,
                       int* __restrict__ S) {
  int i = blockIdx.x * 256 + threadIdx.x;
  int v = (i < NCNT) ? cnt[i] : 0;
  int lane = threadIdx.x & 63, wv = threadIdx.x >> 6;
  int inc = v;
  for (int d = 1; d < 64; d <<= 1) {
    int y = __shfl_up(inc, d);
    if (lane >= d) inc += y;
  }
  __shared__ int ws[4];
  if (lane == 63) ws[wv] = inc;
  __syncthreads();
  int wex = 0;
  for (int k = 0; k < 4; ++k) wex += (k < wv) ? ws[k] : 0;
  int ex = boff[blockIdx.x] + wex + inc - v;
  if (i < NCNT) S[i] = ex;
  if (blockIdx.x == 0 && threadIdx.x == 0) S[NCNT] = 5 * E_EDGES;
}

// pass 2: scatter without atomics
__global__ void scatter_kernel(P5 src, P5 dst, const int* __restrict__ rp,
                               const int* __restrict__ rank, int* __restrict__ ssrc) {
  const int COFF[5] = {0, 60000, 100000, 140000, 180000};
  int r = blockIdx.y;
  int e = blockIdx.x * blockDim.x + threadIdx.x;
  if (e < E_EDGES) {
    int d = dst.p[r][e];
    int idx = rp[COFF[r] + d] + rank[r * E_EDGES + e];
    ssrc[idx] = src.p[r][e];
  }
}

// ---------------- paired mean aggregation: 2 items/wave, 2 gather chains per half ----------------
struct AggTab { const short* src[5]; short* out[5]; };

__global__ void agg_pair(const int* __restrict__ rp, const int* __restrict__ ssrc,
                         AggTab tab, int be0, int be1, int be2, int be3,
                         int r0, int r1, int r2, int r3, int r4) {
  int b = blockIdx.x;
  int r, b0;
  if (b < be0)      { r = r0; b0 = 0; }
  else if (b < be1) { r = r1; b0 = be0; }
  else if (b < be2) { r = r2; b0 = be1; }
  else if (b < be3) { r = r3; b0 = be2; }
  else              { r = r4; b0 = be3; }
  int coff = r == 0 ? 0 : r == 1 ? 60000 : r == 2 ? 100000 : r == 3 ? 140000 : 180000;
  int nrel = r == 0 ? 60000 : r == 4 ? 100000 : 40000;
  const short* xs = r == 0 ? tab.src[0] : r == 1 ? tab.src[1] : r == 2 ? tab.src[2]
                   : r == 3 ? tab.src[3] : tab.src[4];
  short* ob = r == 0 ? tab.out[0] : r == 1 ? tab.out[1] : r == 2 ? tab.out[2]
             : r == 3 ? tab.out[3] : tab.out[4];

  int wid = threadIdx.x >> 6;
  int lane = threadIdx.x & 63;
  int half = lane >> 5, l32 = lane & 31;
  int row = (b - b0) * 8 + wid * 2 + half;
  bool active = row < nrel;
  int item = coff + row;
  int lo = 0, hi = 0;
  if (active) { lo = rp[item]; hi = rp[item + 1]; }

  f32x2 a0[4], a1[4];
#pragma unroll
  for (int k = 0; k < 4; ++k) { a0[k] = (f32x2){0.f, 0.f}; a1[k] = (f32x2){0.f, 0.f}; }
  int e = lo;
  for (; e + 1 < hi; e += 2) {
    int s0 = ssrc[e];
    int s1 = ssrc[e + 1];
    uint4 u0 = *reinterpret_cast<const uint4*>(xs + (size_t)s0 * 256 + l32 * 8);
    uint4 u1 = *reinterpret_cast<const uint4*>(xs + (size_t)s1 * 256 + l32 * 8);
    unsigned d0[4] = {u0.x, u0.y, u0.z, u0.w};
    unsigned d1[4] = {u1.x, u1.y, u1.z, u1.w};
#pragma unroll
    for (int k = 0; k < 4; ++k) {
      a0[k] += (f32x2){__builtin_bit_cast(float, d0[k] << 16),
                       __builtin_bit_cast(float, d0[k] & 0xffff0000u)};
      a1[k] += (f32x2){__builtin_bit_cast(float, d1[k] << 16),
                       __builtin_bit_cast(float, d1[k] & 0xffff0000u)};
    }
  }
  if (e < hi) {
    int s = ssrc[e];
    uint4 u = *reinterpret_cast<const uint4*>(xs + (size_t)s * 256 + l32 * 8);
    unsigned d[4] = {u.x, u.y, u.z, u.w};
#pragma unroll
    for (int k = 0; k < 4; ++k) {
      a0[k] += (f32x2){__builtin_bit_cast(float, d[k] << 16),
                       __builtin_bit_cast(float, d[k] & 0xffff0000u)};
    }
  }
#pragma unroll
  for (int k = 0; k < 4; ++k) a0[k] += a1[k];
  if (active) {
    int c = hi - lo; if (c < 1) c = 1;
    float inv = 1.0f / (float)c;
    short8 o;
#pragma unroll
    for (int k = 0; k < 4; ++k) {
      o[2 * k] = f2bf(a0[k].x * inv);
      o[2 * k + 1] = f2bf(a0[k].y * inv);
    }
    *reinterpret_cast<short8*>(ob + (size_t)row * 256 + l32 * 8) = o;
  }
}

// ---------------- bf16 MFMA GEMM: BM=128, BN=256, BK=32, 2-phase dbuf pipeline ----------------
// fp32 path now fuses global_mean_pool: per-thread run-accumulated atomicAdd into
// pooled_sum (deletes the 41MB c2f write + 41MB pool re-read + pool dispatch).
struct Srcs4 { const short* s[4]; };
struct GArgs {
  Srcs4 srcs; const short* Bt; const float* bias;
  int M; int K; short* outb;
  float* pool; const int* batch;   // fused pooling (layer-2 ch GEMM only)
};

__device__ __forceinline__ void gemm_stage(const GArgs& a, short* sm, int m0,
                                           int k0, int sel, int w, int lane) {
  short* Abuf = sm + sel * 12288;
  short* Bbuf = sm + sel * 12288 + 4096;
  const short* Aq = a.srcs.s[k0 >> 8];
  const int kc = k0 & 255;
  const int M = a.M;
  {
    const int rbase = w * 16;
    const int row = rbase + (lane >> 2);
    const int cs = ((lane & 3) ^ ((row >> 1) & 3)) << 3;   // pre-swizzled source chunk
    int gr = m0 + row; gr = gr < M ? gr : M - 1;
    load_lds16(Aq + (size_t)gr * 256 + kc + cs, &Abuf[rbase * 32]);
  }
#pragma unroll
  for (int rr = 0; rr < 2; ++rr) {
    const int rbase = w * 32 + rr * 16;
    const int row = rbase + (lane >> 2);
    const int cs = ((lane & 3) ^ ((row >> 1) & 3)) << 3;
    load_lds16(a.Bt + (size_t)row * a.K + k0 + cs, &Bbuf[rbase * 32]);
  }
}

__device__ __forceinline__ void gemm_body(const GArgs& a, int bx) {
  __shared__ short sm[24576];
  const int tid = threadIdx.x;
  const int lane = tid & 63;
  const int w = tid >> 6;             // 0..7
  const int wr = w >> 2, wc = w & 3;  // 2 x 4 wave grid
  const int m0 = bx * 128;
  const int M = a.M, K = a.K;

  f32x4 acc[4][4];
#pragma unroll
  for (int i = 0; i < 4; ++i)
#pragma unroll
    for (int j = 0; j < 4; ++j) acc[i][j] = (f32x4){0.f, 0.f, 0.f, 0.f};

  const int nt = K >> 5;
  gemm_stage(a, sm, m0, 0, 0, w, lane);
  __syncthreads();
  int sel = 0;
  for (int t = 0; t < nt; ++t) {
    if (t + 1 < nt) gemm_stage(a, sm, m0, (t + 1) << 5, sel ^ 1, w, lane);
    {
      const short* Abuf = sm + sel * 12288;
      const short* Bbuf = sm + sel * 12288 + 4096;
      const int cg = lane >> 4;                      // k-chunk 0..3
      bf16x8 af[4], bfr[4];
#pragma unroll
      for (int mi = 0; mi < 4; ++mi) {
        const int r = wr * 64 + mi * 16 + (lane & 15);
        af[mi] = *reinterpret_cast<const bf16x8*>(&Abuf[r * 32 + ((cg ^ ((r >> 1) & 3)) << 3)]);
      }
#pragma unroll
      for (int nj = 0; nj < 4; ++nj) {
        const int r = wc * 64 + nj * 16 + (lane & 15);
        bfr[nj] = *reinterpret_cast<const bf16x8*>(&Bbuf[r * 32 + ((cg ^ ((r >> 1) & 3)) << 3)]);
      }
#pragma unroll
      for (int mi = 0; mi < 4; ++mi)
#pragma unroll
        for (int nj = 0; nj < 4; ++nj)
          acc[mi][nj] = __builtin_amdgcn_mfma_f32_16x16x32_bf16(af[mi], bfr[nj], acc[mi][nj], 0, 0, 0);
    }
    __syncthreads();   // drains prefetch loads (vmcnt) + protects buffer reuse
    sel ^= 1;
  }

  const int rb = (lane >> 4) << 2;
  const int cl = lane & 15;

  if (a.outb) {
#pragma unroll
    for (int halfp = 0; halfp < 2; ++halfp) {
      __syncthreads();
      if (wr == halfp) {
#pragma unroll
        for (int mi = 0; mi < 4; ++mi)
#pragma unroll
          for (int nj = 0; nj < 4; ++nj) {
            const int col = wc * 64 + nj * 16 + cl;
            const float bv = a.bias[col];
#pragma unroll
            for (int j = 0; j < 4; ++j) {
              const int rloc = mi * 16 + rb + j;
              float v = fmaxf(acc[mi][nj][j] + bv, 0.0f);
              sm[rloc * 264 + col] = f2bf(v);
            }
          }
      }
      __syncthreads();
#pragma unroll
      for (int q = 0; q < 4; ++q) {
        int c = q * 512 + tid;
        int rloc = c >> 5;
        int coff = (c & 31) * 8;
        int grow = m0 + halfp * 64 + rloc;
        if (grow < M) {
          short8 vv = *reinterpret_cast<const short8*>(&sm[rloc * 264 + coff]);
          *reinterpret_cast<short8*>(a.outb + (size_t)grow * 256 + coff) = vv;
        }
      }
    }
  }
  if (a.pool) {
    // fused global_mean_pool (sum part): thread owns 4 cols x 4 rows per pass,
    // run-accumulates over sorted batch ids, ~1-2 atomicAdd flushes per thread.
    float* fsm = reinterpret_cast<float*>(sm);
    const int col4 = (tid & 63) * 4;
    const int rgrp = tid >> 6;          // 0..7
    f32x4 pacc = (f32x4){0.f, 0.f, 0.f, 0.f};
    int pb = -1;
#pragma unroll
    for (int p = 0; p < 4; ++p) {
      __syncthreads();
      if (wr == (p >> 1)) {
#pragma unroll
        for (int mm = 0; mm < 2; ++mm) {
          const int mi = (p & 1) * 2 + mm;
#pragma unroll
          for (int nj = 0; nj < 4; ++nj) {
            const int col = wc * 64 + nj * 16 + cl;
            const float bv = a.bias[col];
#pragma unroll
            for (int j = 0; j < 4; ++j) {
              const int rloc = mi * 16 + rb + j - (p & 1) * 32;
              float v = fmaxf(acc[mi][nj][j] + bv, 0.0f);
              fsm[rloc * 260 + col] = v;
            }
          }
        }
      }
      __syncthreads();
#pragma unroll
      for (int j = 0; j < 4; ++j) {
        int rloc = rgrp * 4 + j;
        int grow = m0 + p * 32 + rloc;
        if (grow < M) {
          int bb = a.batch[grow];
          f32x4 v = *reinterpret_cast<const f32x4*>(&fsm[rloc * 260 + col4]);
          if (bb != pb) {
            if (pb >= 0) {
              atomicAdd(&a.pool[pb * 256 + col4 + 0], pacc[0]);
              atomicAdd(&a.pool[pb * 256 + col4 + 1], pacc[1]);
              atomicAdd(&a.pool[pb * 256 + col4 + 2], pacc[2]);
              atomicAdd(&a.pool[pb * 256 + col4 + 3], pacc[3]);
            }
            pacc = v; pb = bb;
          } else {
            pacc += v;
          }
        }
      }
    }
    if (pb >= 0) {
      atomicAdd(&a.pool[pb * 256 + col4 + 0], pacc[0]);
      atomicAdd(&a.pool[pb * 256 + col4 + 1], pacc[1]);
      atomicAdd(&a.pool[pb * 256 + col4 + 2], pacc[2]);
      atomicAdd(&a.pool[pb * 256 + col4 + 3], pacc[3]);
    }
  }
}

__global__ __launch_bounds__(512) void gemm_bt(GArgs a) {
  gemm_body(a, blockIdx.x);
}

__global__ __launch_bounds__(512) void gemm_multi3(GArgs a0, GArgs a1, GArgs a2,
                                                   int nb0, int nb01) {
  int bx = blockIdx.x;
  if (bx < nb0) gemm_body(a0, bx);
  else if (bx < nb01) gemm_body(a1, bx - nb0);
  else gemm_body(a2, bx - nb01);
}

// ---------------- MLP (reads pooled sums, divides by counts) ----------------
__device__ __forceinline__ int lower_bound(const int* a, int n, int v) {
  int lo = 0, hi = n;
  while (lo < hi) { int mid = (lo + hi) >> 1; if (a[mid] < v) lo = mid + 1; else hi = mid; }
  return lo;
}

__global__ void mlp_kernel(const float* __restrict__ pooled_sum, const int* __restrict__ batch,
                           const float* __restrict__ train,
                           const float* __restrict__ fc1w, const float* __restrict__ fc1b,
                           const float* __restrict__ fc2w, const float* __restrict__ fc2b,
                           float* __restrict__ out) {
  int b = blockIdx.x, t = threadIdx.x;
  __shared__ float x[288];
  __shared__ float hsm[128];
  __shared__ float sinv;
  if (t == 0) {
    int lo = lower_bound(batch, NCH, b);
    int hi = lower_bound(batch, NCH, b + 1);
    int c = hi - lo; if (c < 1) c = 1;
    sinv = 1.0f / (float)c;
  }
  __syncthreads();
  float inv = sinv;
  x[t] = pooled_sum[b * 256 + t] * inv;
  x[128 + t] = pooled_sum[b * 256 + 128 + t] * inv;
  if (t < 32) x[256 + t] = train[b * 32 + t];
  __syncthreads();
  float s = fc1b[t];
  for (int i = 0; i < 288; ++i) s += x[i] * fc1w[i * 128 + t];
  hsm[t] = fmaxf(s, 0.f);
  __syncthreads();
  if (t < 16) {
    float o = fc2b[t];
    for (int i = 0; i < 128; ++i) o += hsm[i] * fc2w[i * 16 + t];
    out[b * 16 + t] = o;
  }
}

// ---------------- launch ----------------
extern "C" void kernel_launch(void* const* d_in, const int* in_sizes, int n_in,
                              void* d_out, int out_size, void* d_ws, size_t ws_size,
                              hipStream_t stream) {
  const float* x_hru = (const float*)d_in[0];
  const float* x_ch  = (const float*)d_in[1];
  const float* x_gw  = (const float*)d_in[2];
  const int* src_swgw = (const int*)d_in[3];
  const int* dst_swgw = (const int*)d_in[4];
  const int* src_hyd  = (const int*)d_in[5];
  const int* dst_hyd  = (const int*)d_in[6];
  const int* src_sw   = (const int*)d_in[7];
  const int* dst_sw   = (const int*)d_in[8];
  const int* src_gwsw = (const int*)d_in[9];
  const int* dst_gwsw = (const int*)d_in[10];
  const int* src_slf  = (const int*)d_in[11];
  const int* dst_slf  = (const int*)d_in[12];
  const int* batch    = (const int*)d_in[13];
  const float* train  = (const float*)d_in[14];
  const float* Wl     = (const float*)d_in[15];
  const float* Wr     = (const float*)d_in[16];
  const float* bs     = (const float*)d_in[17];
  const float* fc1w   = (const float*)d_in[18];
  const float* fc1b   = (const float*)d_in[19];
  const float* fc2w   = (const float*)d_in[20];
  const float* fc2b   = (const float*)d_in[21];
  float* out = (float*)d_out;

  char* ws = (char*)d_ws;
  size_t off = 0;
  auto alloc = [&](size_t bytes) -> void* {
    off = (off + 255) & ~(size_t)255;
    void* p = ws + off;
    off += bytes;
    return p;
  };

  short* xb0h = (short*)alloc((size_t)NHRU * 256 * 2);
  short* xb0c = (short*)alloc((size_t)NCH * 256 * 2);
  short* xb0g = (short*)alloc((size_t)NGW * 256 * 2);
  short* xb1h = (short*)alloc((size_t)NHRU * 256 * 2);
  short* xb1c = (short*)alloc((size_t)NCH * 256 * 2);
  short* xb1g = (short*)alloc((size_t)NGW * 256 * 2);
  short* agg_gw  = (short*)alloc((size_t)NGW * 256 * 2);
  short* agg_c0  = (short*)alloc((size_t)NCH * 256 * 2);
  short* agg_c1  = (short*)alloc((size_t)NCH * 256 * 2);
  short* agg_c2  = (short*)alloc((size_t)NCH * 256 * 2);
  short* agg_hru = (short*)alloc((size_t)NHRU * 256 * 2);
  int* cnt  = (int*)alloc(NCNT * 4);
  int* rp   = (int*)alloc((NCNT + 1) * 4);
  int* rank = (int*)alloc((size_t)5 * E_EDGES * 4);
  int* bsum = (int*)alloc(NBLK_SCAN * 4);
  int* boff = (int*)alloc(NBLK_SCAN * 4);
  int* ssrc = (int*)alloc((size_t)5 * E_EDGES * 4);
  short* BtBuf = (short*)alloc(786432 * 2);
  float* biasBuf = (float*)alloc(1024 * 4);
  float* pooled_sum = (float*)alloc(64 * 256 * 4);

  hipMemsetAsync(cnt, 0, NCNT * 4, stream);
  hipMemsetAsync(pooled_sum, 0, 64 * 256 * 4, stream);

  P5 dsts; dsts.p[0] = dst_swgw; dsts.p[1] = dst_hyd; dsts.p[2] = dst_sw;
  dsts.p[3] = dst_gwsw; dsts.p[4] = dst_slf;
  P5 srcs; srcs.p[0] = src_swgw; srcs.p[1] = src_hyd; srcs.p[2] = src_sw;
  srcs.p[3] = src_gwsw; srcs.p[4] = src_slf;

  // fused front-end: cvt (+intra-block count) | prep_w
  fused_pre<<<NB_CVT + NB_PREP, 256, 0, stream>>>(
      x_hru, x_ch, x_gw, xb0h, xb0c, xb0g,
      Wl, Wr, bs, BtBuf, biasBuf, dsts, cnt, rank);

  scan_a<<<NBLK_SCAN, 256, 0, stream>>>(cnt, bsum);
  scan_b<<<1, 1024, 0, stream>>>(bsum, boff);
  scan_c<<<NBLK_SCAN, 256, 0, stream>>>(cnt, boff, rp);
  dim3 eg(NB_E, 5);
  scatter_kernel<<<eg, 256, 0, stream>>>(srcs, dsts, rp, rank, ssrc);

  // layer 1: all 5 relations, single dispatch
  {
    AggTab t0{};
    t0.src[0] = xb0h; t0.out[0] = agg_gw;
    t0.src[1] = xb0c; t0.out[1] = agg_c0;
    t0.src[2] = xb0h; t0.out[2] = agg_c1;
    t0.src[3] = xb0g; t0.out[3] = agg_c2;
    t0.src[4] = xb0h; t0.out[4] = agg_hru;
    agg_pair<<<35000, 256, 0, stream>>>(rp, ssrc, t0, 7500, 12500, 17500, 22500, 0, 1, 2, 3, 4);
  }

  // layer 1 GEMMs (merged, ch-first: ch | gw | hru)
  {
    GArgs g0{}, g1{}, g2{};
    g0.srcs.s[0] = agg_c0; g0.srcs.s[1] = agg_c1; g0.srcs.s[2] = agg_c2; g0.srcs.s[3] = xb0c;
    g0.Bt = BtBuf + 131072; g0.bias = biasBuf + 256; g0.M = NCH; g0.K = 1024;
    g0.outb = xb1c; g0.pool = nullptr; g0.batch = nullptr;
    g1.srcs.s[0] = agg_gw; g1.srcs.s[1] = xb0g;
    g1.Bt = BtBuf + 0; g1.bias = biasBuf + 0; g1.M = NGW; g1.K = 512;
    g1.outb = xb1g; g1.pool = nullptr; g1.batch = nullptr;
    g2.srcs.s[0] = agg_hru; g2.srcs.s[1] = xb0h;
    g2.Bt = BtBuf + 393216; g2.bias = biasBuf + 512; g2.M = NHRU; g2.K = 512;
    g2.outb = xb1h; g2.pool = nullptr; g2.batch = nullptr;
    const int nb0 = (NCH + 127) / 128;
    const int nb1 = (NGW + 127) / 128;
    const int nb2 = (NHRU + 127) / 128;
    gemm_multi3<<<dim3(nb0 + nb1 + nb2), 512, 0, stream>>>(g0, g1, g2, nb0, nb0 + nb1);
  }

  // layer 2: channel-dst relations (hyd, sw, gwsw), single dispatch
  {
    AggTab t1{};
    t1.src[1] = xb1c; t1.out[1] = agg_c0;
    t1.src[2] = xb1h; t1.out[2] = agg_c1;
    t1.src[3] = xb1g; t1.out[3] = agg_c2;
    agg_pair<<<15000, 256, 0, stream>>>(rp, ssrc, t1, 5000, 10000, 15000, 15000, 1, 2, 3, 3, 3);
  }

  // layer 2 channel GEMM with fused pooling -> pooled_sum
  {
    GArgs g{};
    g.srcs.s[0] = agg_c0; g.srcs.s[1] = agg_c1; g.srcs.s[2] = agg_c2; g.srcs.s[3] = xb1c;
    g.Bt = BtBuf + 524288; g.bias = biasBuf + 768; g.M = NCH; g.K = 1024;
    g.outb = nullptr; g.pool = pooled_sum; g.batch = batch;
    gemm_bt<<<dim3((NCH + 127) / 128), 512, 0, stream>>>(g);
  }

  mlp_kernel<<<64, 128, 0, stream>>>(pooled_sum, batch, train, fc1w, fc1b, fc2w, fc2b, out);

  (void)in_sizes; (void)n_in; (void)out_size; (void)ws_size;
}